// Round 5
// baseline (924.179 us; speedup 1.0000x reference)
//
#include <hip/hip_runtime.h>
#include <hip/hip_bf16.h>
#include <math.h>

#define HH  256      // d_model
#define NHD 32       // state halves
#define LL  8192     // sequence length
#define BB  16       // batch
#define HN  (HH*NHD) // 8192
#define BH  (BB*HH)  // 4096
#define LC  512      // chunk length
#define NG  (LL/LC)  // 16 chunks per row
#define NIT (LC/16)  // 32 sub-iters per chunk

typedef __attribute__((ext_vector_type(8))) short short8;
typedef __attribute__((ext_vector_type(4))) float floatx4;
typedef __attribute__((ext_vector_type(2))) float f32x2;

// ---------------------------------------------------------------------------
// packed f32 math (kept from R3: measured issue-rate-neutral, numerics fine)
// ---------------------------------------------------------------------------
__device__ __forceinline__ f32x2 pk_fma(f32x2 a, f32x2 b, f32x2 c) {
  f32x2 d;
  asm("v_pk_fma_f32 %0, %1, %2, %3" : "=v"(d) : "v"(a), "v"(b), "v"(c));
  return d;
}
__device__ __forceinline__ f32x2 pk_mul(f32x2 a, f32x2 b) {
  f32x2 d;
  asm("v_pk_mul_f32 %0, %1, %2" : "=v"(d) : "v"(a), "v"(b));
  return d;
}
__device__ __forceinline__ void pk_fma_acc(f32x2& c, f32x2 a, f32x2 b) {
  asm("v_pk_fma_f32 %0, %1, %2, %0" : "+v"(c) : "v"(a), "v"(b));
}

// bf16 round-to-nearest-even helpers
__device__ __forceinline__ unsigned short f2bf(float f) {
  unsigned u = __float_as_uint(f);
  unsigned r = (u + 0x7FFF + ((u >> 16) & 1)) >> 16;
  return (unsigned short)r;
}
__device__ __forceinline__ float bf2f(unsigned short s) {
  return __uint_as_float((unsigned)s << 16);
}

// ---------------------------------------------------------------------------
// Param precompute
// ---------------------------------------------------------------------------
__global__ void precomp_kernel(const float* __restrict__ log_dt,
                               const float* __restrict__ A_real,
                               const float* __restrict__ A_imag,
                               const float* __restrict__ C_real,
                               const float* __restrict__ C_imag,
                               float* __restrict__ P) {
  int i = blockIdx.x * blockDim.x + threadIdx.x;
  if (i >= HN) return;
  int h = i >> 5;
  double dt  = exp((double)log_dt[h]);
  double Are = -exp((double)A_real[i]);
  double Aim = (double)A_imag[i];
  double ar = Are * dt, ai = Aim * dt;
  double ea = exp(ar);
  double wr = ea * cos(ai), wi = ea * sin(ai);
  double em_r = wr - 1.0, em_i = wi;
  double den = Are * Are + Aim * Aim;
  double rr = (em_r * Are + em_i * Aim) / den;
  double ri = (em_i * Are - em_r * Aim) / den;
  P[0*HN + i] = (float)wr;
  P[1*HN + i] = (float)wi;
  {
    double cr = (double)C_real[i], ci = (double)C_imag[i];
    P[2*HN + i] = (float)(2.0 * (cr * rr - ci * ri));
    P[3*HN + i] = (float)(2.0 * (cr * ri + ci * rr));
  }
  {
    double cr = (double)C_real[HN + i], ci = (double)C_imag[HN + i];
    P[4*HN + i] = (float)(2.0 * (cr * rr - ci * ri));
    P[5*HN + i] = (float)(2.0 * (cr * ri + ci * rr));
  }
  {
    double arL = ar * (double)LC, aiL = ai * (double)LC;
    double eaL = exp(arL);
    P[6*HN + i] = (float)(eaL * cos(aiL));
    P[7*HN + i] = (float)(eaL * sin(aiL));
  }
}

// ---------------------------------------------------------------------------
// W_out (512,256) -> WT (256,512)  [fallback path]
// ---------------------------------------------------------------------------
__global__ void wt_kernel(const float* __restrict__ W, float* __restrict__ WT) {
  int idx = blockIdx.x * blockDim.x + threadIdx.x;
  if (idx >= 512 * HH) return;
  int o = idx & 511, h = idx >> 9;
  WT[idx] = W[o * HH + h];
}

// W (512,256) row-major -> bf16 hi/lo planes
__global__ void wt_split_kernel(const float* __restrict__ W,
                                unsigned short* __restrict__ Whi,
                                unsigned short* __restrict__ Wlo) {
  int idx = blockIdx.x * 256 + threadIdx.x;
  float v = W[idx];
  unsigned short hi = f2bf(v);
  Whi[idx] = hi;
  Wlo[idx] = f2bf(v - bf2f(hi));
}

// ---------------------------------------------------------------------------
// x (L, B*H) -> U (B*H, L)  tiled transpose
// ---------------------------------------------------------------------------
__global__ void transpose_kernel(const float* __restrict__ x, float* __restrict__ U) {
  __shared__ float tile[32][33];
  int gx = blockIdx.x * 32;
  int gy = blockIdx.y * 32;
  int tx = threadIdx.x, ty = threadIdx.y;
  #pragma unroll
  for (int k2 = 0; k2 < 4; ++k2)
    tile[ty + 8*k2][tx] = x[(size_t)(gy + ty + 8*k2) * BH + gx + tx];
  __syncthreads();
  #pragma unroll
  for (int k2 = 0; k2 < 4; ++k2)
    U[(size_t)(gx + ty + 8*k2) * LL + gy + tx] = tile[tx][ty + 8*k2];
}

// ---------------------------------------------------------------------------
// U (B*H, L) f32 -> Yhi/Ylo (B*L, H) bf16 planes
// ---------------------------------------------------------------------------
__global__ void convT_kernel(const float* __restrict__ U,
                             unsigned short* __restrict__ Yhi,
                             unsigned short* __restrict__ Ylo) {
  __shared__ float tile[32][33];
  int pb = blockIdx.x * 32;
  int lb = blockIdx.y * 32;
  int tx = threadIdx.x, ty = threadIdx.y;
  #pragma unroll
  for (int k2 = 0; k2 < 4; ++k2)
    tile[ty + 8*k2][tx] = U[(size_t)(pb + ty + 8*k2) * LL + lb + tx];
  __syncthreads();
  int b = pb >> 8, h0 = pb & 255;
  #pragma unroll
  for (int k2 = 0; k2 < 4; ++k2) {
    int r = ty + 8*k2;
    float v = tile[tx][r];
    size_t o = (size_t)(b * LL + lb + r) * HH + h0 + tx;
    unsigned short hi = f2bf(v);
    Yhi[o] = hi;
    Ylo[o] = f2bf(v - bf2f(hi));
  }
}

// ---------------------------------------------------------------------------
// quad (4-lane) DPP helpers
// ---------------------------------------------------------------------------
template<int CTRL>
__device__ __forceinline__ float qbcast(float v) {
  int t = __builtin_amdgcn_update_dpp(0, __float_as_int(v), CTRL, 0xF, 0xF, true);
  return __int_as_float(t);
}
template<int CTRL>
__device__ __forceinline__ float qadd(float v) {
  int t = __builtin_amdgcn_update_dpp(0, __float_as_int(v), CTRL, 0xF, 0xF, true);
  return v + __int_as_float(t);
}

// ---------------------------------------------------------------------------
// packed step primitives: 8 complex states per lane as 4 pairs
// ---------------------------------------------------------------------------
__device__ __forceinline__ void upd4(f32x2 (&sr)[4], f32x2 (&si)[4],
                                     const f32x2 (&wr)[4], const f32x2 (&wi)[4],
                                     const f32x2 (&nwi)[4], float ub) {
  f32x2 u2; u2[0] = ub; u2[1] = ub;
  #pragma unroll
  for (int j = 0; j < 4; ++j) {
    f32x2 t   = pk_fma(wr[j], sr[j], u2);
    f32x2 m   = pk_mul(wr[j], si[j]);
    f32x2 srn = pk_fma(nwi[j], si[j], t);
    si[j] = pk_fma(wi[j], sr[j], m);
    sr[j] = srn;
  }
}
__device__ __forceinline__ float out4(const f32x2 (&sr)[4], const f32x2 (&si)[4],
                                      const f32x2 (&cr)[4], const f32x2 (&nci)[4]) {
  f32x2 a = pk_mul(cr[0], sr[0]);
  f32x2 b = pk_mul(nci[0], si[0]);
  pk_fma_acc(a, cr[1], sr[1]);  pk_fma_acc(b, nci[1], si[1]);
  pk_fma_acc(a, cr[2], sr[2]);  pk_fma_acc(b, nci[2], si[2]);
  pk_fma_acc(a, cr[3], sr[3]);  pk_fma_acc(b, nci[3], si[3]);
  return (a[0] + a[1]) + (b[0] + b[1]);
}

// ---------------------------------------------------------------------------
// Pass A: per-(row,chunk) local final states, both directions, zero init.
// ---------------------------------------------------------------------------
__global__ __launch_bounds__(256) void scanA(const float* __restrict__ U,
                                             const float* __restrict__ P,
                                             float* __restrict__ SF,
                                             float* __restrict__ SB) {
  int tid = threadIdx.x;
  int gl  = tid & 3;
  int grp = (blockIdx.x << 6) | (tid >> 2);
  int p = grp >> 4, g = grp & (NG - 1), h = p & (HH - 1);
  const float* Pb = P + h * NHD + gl * 8;
  f32x2 wr2[4], wi2[4], nwi2[4];
  #pragma unroll
  for (int j = 0; j < 4; ++j) {
    wr2[j] = ((const f32x2*)Pb)[j];
    wi2[j] = ((const f32x2*)(Pb + HN))[j];
    nwi2[j] = -wi2[j];
  }
  f32x2 fr2[4], fi2[4], br2[4], bi2[4];
  #pragma unroll
  for (int j = 0; j < 4; ++j) {
    fr2[j] = (f32x2){0.f, 0.f}; fi2[j] = (f32x2){0.f, 0.f};
    br2[j] = (f32x2){0.f, 0.f}; bi2[j] = (f32x2){0.f, 0.f};
  }
  size_t base = (size_t)p * LL + (size_t)g * LC;
  const float* up = U + base;

#define AF(J2, CMP) { float ubv = qbcast<(J2)*0x55>(uf.CMP); upd4(fr2, fi2, wr2, wi2, nwi2, ubv); }
#define AB(J2, CMP) { float ubv = qbcast<(J2)*0x55>(ub4.CMP); upd4(br2, bi2, wr2, wi2, nwi2, ubv); }
  for (int ii = 0; ii < NIT; ++ii) {
    float4 uf  = ((const float4*)(up + 16 * ii))[gl];
    float4 ub4 = ((const float4*)(up + (LC - 16) - 16 * ii))[gl];
    AF(0,x) AF(0,y) AF(0,z) AF(0,w)
    AF(1,x) AF(1,y) AF(1,z) AF(1,w)
    AF(2,x) AF(2,y) AF(2,z) AF(2,w)
    AF(3,x) AF(3,y) AF(3,z) AF(3,w)
    AB(3,w) AB(3,z) AB(3,y) AB(3,x)
    AB(2,w) AB(2,z) AB(2,y) AB(2,x)
    AB(1,w) AB(1,z) AB(1,y) AB(1,x)
    AB(0,w) AB(0,z) AB(0,y) AB(0,x)
  }
#undef AF
#undef AB
  float4* of = (float4*)(SF + (size_t)grp * 64 + gl * 16);
  float4* ob = (float4*)(SB + (size_t)grp * 64 + gl * 16);
  #pragma unroll
  for (int j = 0; j < 4; ++j) {
    float4 v;
    v.x = fr2[j][0]; v.y = fi2[j][0]; v.z = fr2[j][1]; v.w = fi2[j][1];
    of[j] = v;
    v.x = br2[j][0]; v.y = bi2[j][0]; v.z = br2[j][1]; v.w = bi2[j][1];
    ob[j] = v;
  }
}

// ---------------------------------------------------------------------------
// Pass B: cross-chunk state scan, in place.
// ---------------------------------------------------------------------------
__global__ __launch_bounds__(256) void scanB(const float* __restrict__ P,
                                             float* __restrict__ SF,
                                             float* __restrict__ SB) {
  int t = blockIdx.x * 256 + threadIdx.x;
  if (t >= BH * NHD) return;
  int p = t >> 5, n = t & 31, h = p & (HH - 1);
  float wlr = P[6*HN + h*NHD + n], wli = P[7*HN + h*NHD + n];
  {
    float* f = SF + (size_t)p * NG * 64 + 2 * n;
    float ar = 0.f, ai = 0.f;
    for (int g = 0; g < NG; ++g) {
      float lr = f[g*64], li = f[g*64+1];
      f[g*64] = ar; f[g*64+1] = ai;
      float nr = lr + wlr * ar - wli * ai;
      float ni = li + wlr * ai + wli * ar;
      ar = nr; ai = ni;
    }
  }
  {
    float* b = SB + (size_t)p * NG * 64 + 2 * n;
    float ar = 0.f, ai = 0.f;
    for (int g = NG - 1; g >= 0; --g) {
      float lr = b[g*64], li = b[g*64+1];
      b[g*64] = ar; b[g*64+1] = ai;
      float nr = lr + wlr * ar - wli * ai;
      float ni = li + wlr * ai + wli * ar;
      ar = nr; ai = ni;
    }
  }
}

// ---------------------------------------------------------------------------
// Pass C backward: y_b partials -> YB (d_out).
// ---------------------------------------------------------------------------
__global__ __launch_bounds__(256) void scanC_bwd(const float* __restrict__ U,
                                                 const float* __restrict__ P,
                                                 const float* __restrict__ Sin,
                                                 float* __restrict__ YB) {
  int tid = threadIdx.x;
  int gl  = tid & 3;
  int grp = (blockIdx.x << 6) | (tid >> 2);
  int p = grp >> 4, g = grp & (NG - 1), h = p & (HH - 1);
  const float* Pb = P + h * NHD + gl * 8;
  f32x2 wr2[4], wi2[4], nwi2[4], cr2[4], nci2[4];
  #pragma unroll
  for (int j = 0; j < 4; ++j) {
    wr2[j]  = ((const f32x2*)Pb)[j];
    wi2[j]  = ((const f32x2*)(Pb + HN))[j];
    nwi2[j] = -wi2[j];
    cr2[j]  = ((const f32x2*)(Pb + 4*HN))[j];
    nci2[j] = -((const f32x2*)(Pb + 5*HN))[j];
  }
  f32x2 sr2[4], si2[4];
  const float* sp = Sin + (size_t)grp * 64 + gl * 16;
  #pragma unroll
  for (int j = 0; j < 4; ++j) {
    sr2[j][0] = sp[4*j];   sr2[j][1] = sp[4*j+2];
    si2[j][0] = sp[4*j+1]; si2[j][1] = sp[4*j+3];
  }
  size_t base = (size_t)p * LL + (size_t)g * LC;
  const float* up = U + base;
  float* yp = YB + base;

#define QB(J2, CMP, ACC) { \
    float ubv = qbcast<(J2)*0x55>(u4.CMP); \
    float c = out4(sr2, si2, cr2, nci2); \
    upd4(sr2, si2, wr2, wi2, nwi2, ubv); \
    c = qadd<0xB1>(c); c = qadd<0x4E>(c); \
    ACC = (gl == (J2)) ? c : ACC; }
  for (int ii = NIT - 1; ii >= 0; --ii) {
    float4 u4 = ((const float4*)(up + 16 * ii))[gl];
    float a0 = 0.f, a1 = 0.f, a2 = 0.f, a3 = 0.f;
    QB(3,w,a3) QB(3,z,a2) QB(3,y,a1) QB(3,x,a0)
    QB(2,w,a3) QB(2,z,a2) QB(2,y,a1) QB(2,x,a0)
    QB(1,w,a3) QB(1,z,a2) QB(1,y,a1) QB(1,x,a0)
    QB(0,w,a3) QB(0,z,a2) QB(0,y,a1) QB(0,x,a0)
    float4 o4; o4.x = a0; o4.y = a1; o4.z = a2; o4.w = a3;
    ((float4*)(yp + 16 * ii))[gl] = o4;
  }
#undef QB
}

// ---------------------------------------------------------------------------
// Pass C forward: combine y_f + y_b + D*u, gelu, write over U in place.
// ---------------------------------------------------------------------------
__device__ __forceinline__ float gelu_t(float y) {
  float y2 = y * y;
  float arg = 1.5957691216f * fmaf(0.044715f * y2, y, y);
  return y / (1.f + __expf(-arg));
}
__global__ __launch_bounds__(256) void scanC_fwd(float* __restrict__ U,
                                                 const float* __restrict__ P,
                                                 const float* __restrict__ Sin,
                                                 const float* __restrict__ YB,
                                                 const float* __restrict__ Dv) {
  int tid = threadIdx.x;
  int gl  = tid & 3;
  int grp = (blockIdx.x << 6) | (tid >> 2);
  int p = grp >> 4, g = grp & (NG - 1), h = p & (HH - 1);
  const float* Pb = P + h * NHD + gl * 8;
  f32x2 wr2[4], wi2[4], nwi2[4], cr2[4], nci2[4];
  #pragma unroll
  for (int j = 0; j < 4; ++j) {
    wr2[j]  = ((const f32x2*)Pb)[j];
    wi2[j]  = ((const f32x2*)(Pb + HN))[j];
    nwi2[j] = -wi2[j];
    cr2[j]  = ((const f32x2*)(Pb + 2*HN))[j];
    nci2[j] = -((const f32x2*)(Pb + 3*HN))[j];
  }
  float dh = Dv[h];
  f32x2 sr2[4], si2[4];
  const float* sp = Sin + (size_t)grp * 64 + gl * 16;
  #pragma unroll
  for (int j = 0; j < 4; ++j) {
    sr2[j][0] = sp[4*j];   sr2[j][1] = sp[4*j+2];
    si2[j][0] = sp[4*j+1]; si2[j][1] = sp[4*j+3];
  }
  size_t base = (size_t)p * LL + (size_t)g * LC;
  float* up = U + base;
  const float* ybp = YB + base;

#define QF(J2, CMP, ACC) { \
    float ubv = qbcast<(J2)*0x55>(u4.CMP); \
    upd4(sr2, si2, wr2, wi2, nwi2, ubv); \
    float c = out4(sr2, si2, cr2, nci2); \
    c = qadd<0xB1>(c); c = qadd<0x4E>(c); \
    ACC = (gl == (J2)) ? c : ACC; }
  for (int ii = 0; ii < NIT; ++ii) {
    float4 u4  = ((const float4*)(up + 16 * ii))[gl];
    float4 yb4 = ((const float4*)(ybp + 16 * ii))[gl];
    float a0 = 0.f, a1 = 0.f, a2 = 0.f, a3 = 0.f;
    QF(0,x,a0) QF(0,y,a1) QF(0,z,a2) QF(0,w,a3)
    QF(1,x,a0) QF(1,y,a1) QF(1,z,a2) QF(1,w,a3)
    QF(2,x,a0) QF(2,y,a1) QF(2,z,a2) QF(2,w,a3)
    QF(3,x,a0) QF(3,y,a1) QF(3,z,a2) QF(3,w,a3)
    float4 o4;
    o4.x = gelu_t(a0 + yb4.x + dh * u4.x);
    o4.y = gelu_t(a1 + yb4.y + dh * u4.y);
    o4.z = gelu_t(a2 + yb4.z + dh * u4.z);
    o4.w = gelu_t(a3 + yb4.w + dh * u4.w);
    ((float4*)(up + 16 * ii))[gl] = o4;
  }
#undef QF
}

// ---------------------------------------------------------------------------
// MFMA GEMM + GLU, LDS-staged B. Split-bf16: z = Whi*yhi + Whi*ylo + Wlo*yhi.
// Block: 1024 thr (16 waves). Wave w owns o-rows {w*16..+16} u {256+w*16..+16}
// (mm=2) so GLU pairs are lane-local. BN=128 cols, BK=32 slices (8 slices),
// double-buffered LDS [2][plane(2)][col(128)][32k bf16, rows padded to 80B].
// 2-phase pipeline: issue next-slice global loads -> compute current -> barrier
// -> ds_write -> barrier.
// ---------------------------------------------------------------------------
#define SL_PL  10240          // per-plane bytes: 128 * 80
#define SL_SZ  20480          // per-slice bytes (2 planes)
__global__ __launch_bounds__(1024, 4) void gemm_mfma(
    const unsigned short* __restrict__ Whi, const unsigned short* __restrict__ Wlo,
    const unsigned short* __restrict__ Yhi, const unsigned short* __restrict__ Ylo,
    const float* __restrict__ bvec, float* __restrict__ out) {
  __shared__ __align__(16) char lds[2][SL_SZ];
  int tid  = threadIdx.x;
  int w    = tid >> 6;
  int lane = tid & 63;
  int ln = lane & 15, lg = lane >> 4;
  int b  = blockIdx.x >> 6;
  int l0 = (blockIdx.x & 63) << 7;

  const short8* Wh8 = (const short8*)Whi;
  const short8* Wl8 = (const short8*)Wlo;

  // staging geometry: thread t stages one 16B chunk per slice.
  int splane = tid >> 9;             // 0 = hi, 1 = lo
  int scol   = (tid >> 2) & 127;     // N-col within tile
  int schunk = tid & 3;              // which 8-elem chunk of the 32-k slice
  const unsigned short* gs = (splane ? Ylo : Yhi)
      + (((size_t)(b * LL + l0 + scol)) << 8) + schunk * 8;   // + s*32 per slice
  int lofs = splane * SL_PL + scol * 80 + schunk * 16;

  floatx4 acc[2][8];
  #pragma unroll
  for (int m = 0; m < 2; ++m)
    #pragma unroll
    for (int n = 0; n < 8; ++n) acc[m][n] = (floatx4){0.f, 0.f, 0.f, 0.f};

  // prologue: stage slice 0
  {
    float4 s0 = *(const float4*)gs;
    *(float4*)(&lds[0][lofs]) = s0;
  }
  __syncthreads();

  for (int s = 0; s < 8; ++s) {
    float4 nx;
    if (s < 7) nx = *(const float4*)(gs + (s + 1) * 32);   // issue early
    const char* lbase = lds[s & 1];
    // B fragments from LDS (one K=32 step)
    short8 Bh[8], Bl[8];
    #pragma unroll
    for (int nf = 0; nf < 8; ++nf) {
      int cofs = (nf * 16 + ln) * 80 + lg * 16;
      Bh[nf] = *(const short8*)(lbase + cofs);
      Bl[nf] = *(const short8*)(lbase + SL_PL + cofs);
    }
    #pragma unroll
    for (int mm = 0; mm < 2; ++mm) {
      int orow = (mm << 8) + w * 16 + ln;
      size_t ai = (size_t)orow * 32 + s * 4 + lg;   // short8 units
      short8 Ah = Wh8[ai];
      short8 Al = Wl8[ai];
      #pragma unroll
      for (int nf = 0; nf < 8; ++nf)
        acc[mm][nf] = __builtin_amdgcn_mfma_f32_16x16x32_bf16(Ah, Bh[nf], acc[mm][nf], 0, 0, 0);
      #pragma unroll
      for (int nf = 0; nf < 8; ++nf)
        acc[mm][nf] = __builtin_amdgcn_mfma_f32_16x16x32_bf16(Ah, Bl[nf], acc[mm][nf], 0, 0, 0);
      #pragma unroll
      for (int nf = 0; nf < 8; ++nf)
        acc[mm][nf] = __builtin_amdgcn_mfma_f32_16x16x32_bf16(Al, Bh[nf], acc[mm][nf], 0, 0, 0);
    }
    if (s < 7) {
      __syncthreads();
      *(float4*)(&lds[(s + 1) & 1][lofs]) = nx;
      __syncthreads();
    }
  }

  // epilogue: bias + GLU. D layout: col=lane&15, row=(lane>>4)*4+reg.
  int obase = w * 16 + lg * 4;
  #pragma unroll
  for (int r = 0; r < 4; ++r) {
    int o = obase + r;
    float b0 = bvec[o];
    float b1 = bvec[HH + o];
    float* op = out + ((size_t)(b * HH + o)) * LL + l0 + ln;
    #pragma unroll
    for (int nf = 0; nf < 8; ++nf) {
      float z1 = acc[0][nf][r] + b0;
      float z2 = acc[1][nf][r] + b1;
      op[nf * 16] = z1 / (1.f + __expf(-z2));
    }
  }
}

// ---------------------------------------------------------------------------
// Fallback f32 GEMM (used only if ws too small for the MFMA path)
// ---------------------------------------------------------------------------
__global__ __launch_bounds__(256, 4) void gemm_kernel(const float* __restrict__ Y,
                                                      const float* __restrict__ WT,
                                                      const float* __restrict__ bvec,
                                                      float* __restrict__ out) {
  __shared__ float ytile[HH][36];
  int tid = threadIdx.x;
  int b   = blockIdx.x >> 8;
  int l0  = (blockIdx.x & 255) << 5;
  const float* yrow = Y + ((size_t)b * HH + tid) * LL + l0;
  float4* drow = (float4*)&ytile[tid][0];
  #pragma unroll
  for (int jj = 0; jj < 8; ++jj)
    drow[jj] = ((const float4*)yrow)[jj];
  __syncthreads();
  float acc0[32], acc1[32];
  #pragma unroll
  for (int j = 0; j < 32; ++j) { acc0[j] = 0.f; acc1[j] = 0.f; }
  #pragma unroll 2
  for (int h = 0; h < HH; ++h) {
    float w0 = WT[h * 512 + tid];
    float w1 = WT[h * 512 + 256 + tid];
    const float4* r = (const float4*)&ytile[h][0];
    #pragma unroll
    for (int jj = 0; jj < 8; ++jj) {
      float4 y4 = r[jj];
      acc0[4*jj+0] = fmaf(w0, y4.x, acc0[4*jj+0]);
      acc0[4*jj+1] = fmaf(w0, y4.y, acc0[4*jj+1]);
      acc0[4*jj+2] = fmaf(w0, y4.z, acc0[4*jj+2]);
      acc0[4*jj+3] = fmaf(w0, y4.w, acc0[4*jj+3]);
      acc1[4*jj+0] = fmaf(w1, y4.x, acc1[4*jj+0]);
      acc1[4*jj+1] = fmaf(w1, y4.y, acc1[4*jj+1]);
      acc1[4*jj+2] = fmaf(w1, y4.z, acc1[4*jj+2]);
      acc1[4*jj+3] = fmaf(w1, y4.w, acc1[4*jj+3]);
    }
  }
  float b0 = bvec[tid], b1 = bvec[HH + tid];
  float* orow = out + ((size_t)b * HH + tid) * LL + l0;
  #pragma unroll
  for (int j = 0; j < 32; ++j) {
    float z1 = acc0[j] + b0;
    float z2 = acc1[j] + b1;
    orow[j] = z1 * (1.0f / (1.0f + __expf(-z2)));
  }
}

// ---------------------------------------------------------------------------
extern "C" void kernel_launch(void* const* d_in, const int* in_sizes, int n_in,
                              void* d_out, int out_size, void* d_ws, size_t ws_size,
                              hipStream_t stream) {
  const float* x      = (const float*)d_in[0];
  const float* log_dt = (const float*)d_in[1];
  const float* A_real = (const float*)d_in[2];
  const float* A_imag = (const float*)d_in[3];
  const float* C_real = (const float*)d_in[4];
  const float* C_imag = (const float*)d_in[5];
  const float* Dv     = (const float*)d_in[6];
  const float* W      = (const float*)d_in[7];
  const float* bvec   = (const float*)d_in[8];
  float* out = (float*)d_out;

  char* ws = (char*)d_ws;
  float*          P   = (float*)ws;                       // 256 KB
  float*          WT  = (float*)(ws + 262144);            // 512 KB (fallback)
  unsigned short* Whi = (unsigned short*)(ws + 786432);   // 256 KB
  unsigned short* Wlo = (unsigned short*)(ws + 1048576);  // 256 KB
  size_t OFF_U   = (size_t)2 << 20;
  size_t U_BYTES = (size_t)BH * LL * 4;                   // 128 MB
  size_t S_BYTES = (size_t)BH * NG * 64 * 4;              // 16 MB each
  size_t OFF_SF  = OFF_U + U_BYTES;
  size_t OFF_SB  = OFF_SF + S_BYTES;
  size_t OFF_YH  = OFF_SB + S_BYTES;
  size_t Y_BYTES = (size_t)BB * LL * HH * 2;              // 64 MB each
  size_t OFF_YL  = OFF_YH + Y_BYTES;
  size_t NEED    = OFF_YL + Y_BYTES;                      // ~290 MB
  float* U  = (float*)(ws + OFF_U);
  float* SF = (float*)(ws + OFF_SF);
  float* SB = (float*)(ws + OFF_SB);
  unsigned short* Yhi = (unsigned short*)(ws + OFF_YH);
  unsigned short* Ylo = (unsigned short*)(ws + OFF_YL);

  bool mfma_path = (ws_size >= NEED);

  precomp_kernel<<<HN / 256, 256, 0, stream>>>(log_dt, A_real, A_imag, C_real, C_imag, P);
  if (mfma_path)
    wt_split_kernel<<<512, 256, 0, stream>>>(W, Whi, Wlo);
  else
    wt_kernel<<<512, 256, 0, stream>>>(W, WT);
  transpose_kernel<<<dim3(BH / 32, LL / 32), dim3(32, 8), 0, stream>>>(x, U);
  scanA<<<(BH * NG) / 64, 256, 0, stream>>>(U, P, SF, SB);
  scanB<<<(BH * NHD) / 256, 256, 0, stream>>>(P, SF, SB);
  scanC_bwd<<<(BH * NG) / 64, 256, 0, stream>>>(U, P, SB, (float*)d_out);
  scanC_fwd<<<(BH * NG) / 64, 256, 0, stream>>>(U, P, SF, (const float*)d_out, Dv);
  if (mfma_path) {
    convT_kernel<<<dim3(BH / 32, LL / 32), dim3(32, 8), 0, stream>>>(U, Yhi, Ylo);
    gemm_mfma<<<BB * (LL / 128), 1024, 0, stream>>>(Whi, Wlo, Yhi, Ylo, bvec, out);
  } else {
    gemm_kernel<<<BB * (LL / 32), 256, 0, stream>>>(U, WT, bvec, out);
  }
}

// Round 6
// 827.764 us; speedup vs baseline: 1.1165x; 1.1165x over previous
//
#include <hip/hip_runtime.h>
#include <hip/hip_bf16.h>
#include <math.h>

#define HH  256      // d_model
#define NHD 32       // state halves
#define LL  8192     // sequence length
#define BB  16       // batch
#define HN  (HH*NHD) // 8192
#define BH  (BB*HH)  // 4096
#define LC  512      // chunk length
#define NG  (LL/LC)  // 16 chunks per row
#define NIT (LC/16)  // 32 sub-iters per chunk

typedef __attribute__((ext_vector_type(8))) short short8;
typedef __attribute__((ext_vector_type(4))) float floatx4;
typedef __attribute__((ext_vector_type(2))) float f32x2;

// ---------------------------------------------------------------------------
// packed f32 math (issue-rate-neutral on gfx950 per R3 A/B; kept for regs)
// ---------------------------------------------------------------------------
__device__ __forceinline__ f32x2 pk_fma(f32x2 a, f32x2 b, f32x2 c) {
  f32x2 d;
  asm("v_pk_fma_f32 %0, %1, %2, %3" : "=v"(d) : "v"(a), "v"(b), "v"(c));
  return d;
}
__device__ __forceinline__ f32x2 pk_mul(f32x2 a, f32x2 b) {
  f32x2 d;
  asm("v_pk_mul_f32 %0, %1, %2" : "=v"(d) : "v"(a), "v"(b));
  return d;
}
__device__ __forceinline__ void pk_fma_acc(f32x2& c, f32x2 a, f32x2 b) {
  asm("v_pk_fma_f32 %0, %1, %2, %0" : "+v"(c) : "v"(a), "v"(b));
}

// bf16 round-to-nearest-even helpers
__device__ __forceinline__ unsigned short f2bf(float f) {
  unsigned u = __float_as_uint(f);
  unsigned r = (u + 0x7FFF + ((u >> 16) & 1)) >> 16;
  return (unsigned short)r;
}

// ---------------------------------------------------------------------------
// Param precompute
// ---------------------------------------------------------------------------
__global__ void precomp_kernel(const float* __restrict__ log_dt,
                               const float* __restrict__ A_real,
                               const float* __restrict__ A_imag,
                               const float* __restrict__ C_real,
                               const float* __restrict__ C_imag,
                               float* __restrict__ P) {
  int i = blockIdx.x * blockDim.x + threadIdx.x;
  if (i >= HN) return;
  int h = i >> 5;
  double dt  = exp((double)log_dt[h]);
  double Are = -exp((double)A_real[i]);
  double Aim = (double)A_imag[i];
  double ar = Are * dt, ai = Aim * dt;
  double ea = exp(ar);
  double wr = ea * cos(ai), wi = ea * sin(ai);
  double em_r = wr - 1.0, em_i = wi;
  double den = Are * Are + Aim * Aim;
  double rr = (em_r * Are + em_i * Aim) / den;
  double ri = (em_i * Are - em_r * Aim) / den;
  P[0*HN + i] = (float)wr;
  P[1*HN + i] = (float)wi;
  {
    double cr = (double)C_real[i], ci = (double)C_imag[i];
    P[2*HN + i] = (float)(2.0 * (cr * rr - ci * ri));
    P[3*HN + i] = (float)(2.0 * (cr * ri + ci * rr));
  }
  {
    double cr = (double)C_real[HN + i], ci = (double)C_imag[HN + i];
    P[4*HN + i] = (float)(2.0 * (cr * rr - ci * ri));
    P[5*HN + i] = (float)(2.0 * (cr * ri + ci * rr));
  }
  {
    double arL = ar * (double)LC, aiL = ai * (double)LC;
    double eaL = exp(arL);
    P[6*HN + i] = (float)(eaL * cos(aiL));
    P[7*HN + i] = (float)(eaL * sin(aiL));
  }
}

// ---------------------------------------------------------------------------
// W_out (512,256) -> WT (256,512)  [fallback path]
// ---------------------------------------------------------------------------
__global__ void wt_kernel(const float* __restrict__ W, float* __restrict__ WT) {
  int idx = blockIdx.x * blockDim.x + threadIdx.x;
  if (idx >= 512 * HH) return;
  int o = idx & 511, h = idx >> 9;
  WT[idx] = W[o * HH + h];
}

// W (512,256) row-major -> bf16 (RNE), same layout (MFMA path)
__global__ void wt_bf16_kernel(const float* __restrict__ W,
                               unsigned short* __restrict__ Wb) {
  int idx = blockIdx.x * 256 + threadIdx.x;
  Wb[idx] = f2bf(W[idx]);
}

// ---------------------------------------------------------------------------
// x (L, B*H) -> U (B*H, L)  tiled transpose
// ---------------------------------------------------------------------------
__global__ void transpose_kernel(const float* __restrict__ x, float* __restrict__ U) {
  __shared__ float tile[32][33];
  int gx = blockIdx.x * 32;
  int gy = blockIdx.y * 32;
  int tx = threadIdx.x, ty = threadIdx.y;
  #pragma unroll
  for (int k2 = 0; k2 < 4; ++k2)
    tile[ty + 8*k2][tx] = x[(size_t)(gy + ty + 8*k2) * BH + gx + tx];
  __syncthreads();
  #pragma unroll
  for (int k2 = 0; k2 < 4; ++k2)
    U[(size_t)(gx + ty + 8*k2) * LL + gy + tx] = tile[tx][ty + 8*k2];
}

// ---------------------------------------------------------------------------
// U (B*H, L) f32 -> Yb (B*L, H) bf16 (k-contiguous rows for MFMA B-frags)
// ---------------------------------------------------------------------------
__global__ void convT_kernel(const float* __restrict__ U,
                             unsigned short* __restrict__ Yb) {
  __shared__ float tile[32][33];
  int pb = blockIdx.x * 32;
  int lb = blockIdx.y * 32;
  int tx = threadIdx.x, ty = threadIdx.y;
  #pragma unroll
  for (int k2 = 0; k2 < 4; ++k2)
    tile[ty + 8*k2][tx] = U[(size_t)(pb + ty + 8*k2) * LL + lb + tx];
  __syncthreads();
  int b = pb >> 8, h0 = pb & 255;
  #pragma unroll
  for (int k2 = 0; k2 < 4; ++k2) {
    int r = ty + 8*k2;
    size_t o = (size_t)(b * LL + lb + r) * HH + h0 + tx;
    Yb[o] = f2bf(tile[tx][r]);
  }
}

// ---------------------------------------------------------------------------
// quad (4-lane) DPP helpers
// ---------------------------------------------------------------------------
template<int CTRL>
__device__ __forceinline__ float qbcast(float v) {
  int t = __builtin_amdgcn_update_dpp(0, __float_as_int(v), CTRL, 0xF, 0xF, true);
  return __int_as_float(t);
}
template<int CTRL>
__device__ __forceinline__ float qadd(float v) {
  int t = __builtin_amdgcn_update_dpp(0, __float_as_int(v), CTRL, 0xF, 0xF, true);
  return v + __int_as_float(t);
}

// ---------------------------------------------------------------------------
// packed step primitives: 8 complex states per lane as 4 pairs
// ---------------------------------------------------------------------------
__device__ __forceinline__ void upd4(f32x2 (&sr)[4], f32x2 (&si)[4],
                                     const f32x2 (&wr)[4], const f32x2 (&wi)[4],
                                     const f32x2 (&nwi)[4], float ub) {
  f32x2 u2; u2[0] = ub; u2[1] = ub;
  #pragma unroll
  for (int j = 0; j < 4; ++j) {
    f32x2 t   = pk_fma(wr[j], sr[j], u2);
    f32x2 m   = pk_mul(wr[j], si[j]);
    f32x2 srn = pk_fma(nwi[j], si[j], t);
    si[j] = pk_fma(wi[j], sr[j], m);
    sr[j] = srn;
  }
}
__device__ __forceinline__ float out4(const f32x2 (&sr)[4], const f32x2 (&si)[4],
                                      const f32x2 (&cr)[4], const f32x2 (&nci)[4]) {
  f32x2 a = pk_mul(cr[0], sr[0]);
  f32x2 b = pk_mul(nci[0], si[0]);
  pk_fma_acc(a, cr[1], sr[1]);  pk_fma_acc(b, nci[1], si[1]);
  pk_fma_acc(a, cr[2], sr[2]);  pk_fma_acc(b, nci[2], si[2]);
  pk_fma_acc(a, cr[3], sr[3]);  pk_fma_acc(b, nci[3], si[3]);
  return (a[0] + a[1]) + (b[0] + b[1]);
}

// ---------------------------------------------------------------------------
// Pass A: per-(row,chunk) local final states, both directions, zero init.
// ---------------------------------------------------------------------------
__global__ __launch_bounds__(256) void scanA(const float* __restrict__ U,
                                             const float* __restrict__ P,
                                             float* __restrict__ SF,
                                             float* __restrict__ SB) {
  int tid = threadIdx.x;
  int gl  = tid & 3;
  int grp = (blockIdx.x << 6) | (tid >> 2);
  int p = grp >> 4, g = grp & (NG - 1), h = p & (HH - 1);
  const float* Pb = P + h * NHD + gl * 8;
  f32x2 wr2[4], wi2[4], nwi2[4];
  #pragma unroll
  for (int j = 0; j < 4; ++j) {
    wr2[j] = ((const f32x2*)Pb)[j];
    wi2[j] = ((const f32x2*)(Pb + HN))[j];
    nwi2[j] = -wi2[j];
  }
  f32x2 fr2[4], fi2[4], br2[4], bi2[4];
  #pragma unroll
  for (int j = 0; j < 4; ++j) {
    fr2[j] = (f32x2){0.f, 0.f}; fi2[j] = (f32x2){0.f, 0.f};
    br2[j] = (f32x2){0.f, 0.f}; bi2[j] = (f32x2){0.f, 0.f};
  }
  size_t base = (size_t)p * LL + (size_t)g * LC;
  const float* up = U + base;

#define AF(J2, CMP) { float ubv = qbcast<(J2)*0x55>(uf.CMP); upd4(fr2, fi2, wr2, wi2, nwi2, ubv); }
#define AB(J2, CMP) { float ubv = qbcast<(J2)*0x55>(ub4.CMP); upd4(br2, bi2, wr2, wi2, nwi2, ubv); }
  for (int ii = 0; ii < NIT; ++ii) {
    float4 uf  = ((const float4*)(up + 16 * ii))[gl];
    float4 ub4 = ((const float4*)(up + (LC - 16) - 16 * ii))[gl];
    AF(0,x) AF(0,y) AF(0,z) AF(0,w)
    AF(1,x) AF(1,y) AF(1,z) AF(1,w)
    AF(2,x) AF(2,y) AF(2,z) AF(2,w)
    AF(3,x) AF(3,y) AF(3,z) AF(3,w)
    AB(3,w) AB(3,z) AB(3,y) AB(3,x)
    AB(2,w) AB(2,z) AB(2,y) AB(2,x)
    AB(1,w) AB(1,z) AB(1,y) AB(1,x)
    AB(0,w) AB(0,z) AB(0,y) AB(0,x)
  }
#undef AF
#undef AB
  float4* of = (float4*)(SF + (size_t)grp * 64 + gl * 16);
  float4* ob = (float4*)(SB + (size_t)grp * 64 + gl * 16);
  #pragma unroll
  for (int j = 0; j < 4; ++j) {
    float4 v;
    v.x = fr2[j][0]; v.y = fi2[j][0]; v.z = fr2[j][1]; v.w = fi2[j][1];
    of[j] = v;
    v.x = br2[j][0]; v.y = bi2[j][0]; v.z = br2[j][1]; v.w = bi2[j][1];
    ob[j] = v;
  }
}

// ---------------------------------------------------------------------------
// Pass B: cross-chunk state scan, in place.
// ---------------------------------------------------------------------------
__global__ __launch_bounds__(256) void scanB(const float* __restrict__ P,
                                             float* __restrict__ SF,
                                             float* __restrict__ SB) {
  int t = blockIdx.x * 256 + threadIdx.x;
  if (t >= BH * NHD) return;
  int p = t >> 5, n = t & 31, h = p & (HH - 1);
  float wlr = P[6*HN + h*NHD + n], wli = P[7*HN + h*NHD + n];
  {
    float* f = SF + (size_t)p * NG * 64 + 2 * n;
    float ar = 0.f, ai = 0.f;
    for (int g = 0; g < NG; ++g) {
      float lr = f[g*64], li = f[g*64+1];
      f[g*64] = ar; f[g*64+1] = ai;
      float nr = lr + wlr * ar - wli * ai;
      float ni = li + wlr * ai + wli * ar;
      ar = nr; ai = ni;
    }
  }
  {
    float* b = SB + (size_t)p * NG * 64 + 2 * n;
    float ar = 0.f, ai = 0.f;
    for (int g = NG - 1; g >= 0; --g) {
      float lr = b[g*64], li = b[g*64+1];
      b[g*64] = ar; b[g*64+1] = ai;
      float nr = lr + wlr * ar - wli * ai;
      float ni = li + wlr * ai + wli * ar;
      ar = nr; ai = ni;
    }
  }
}

// ---------------------------------------------------------------------------
// Pass C backward: y_b partials -> YB (d_out).
// ---------------------------------------------------------------------------
__global__ __launch_bounds__(256) void scanC_bwd(const float* __restrict__ U,
                                                 const float* __restrict__ P,
                                                 const float* __restrict__ Sin,
                                                 float* __restrict__ YB) {
  int tid = threadIdx.x;
  int gl  = tid & 3;
  int grp = (blockIdx.x << 6) | (tid >> 2);
  int p = grp >> 4, g = grp & (NG - 1), h = p & (HH - 1);
  const float* Pb = P + h * NHD + gl * 8;
  f32x2 wr2[4], wi2[4], nwi2[4], cr2[4], nci2[4];
  #pragma unroll
  for (int j = 0; j < 4; ++j) {
    wr2[j]  = ((const f32x2*)Pb)[j];
    wi2[j]  = ((const f32x2*)(Pb + HN))[j];
    nwi2[j] = -wi2[j];
    cr2[j]  = ((const f32x2*)(Pb + 4*HN))[j];
    nci2[j] = -((const f32x2*)(Pb + 5*HN))[j];
  }
  f32x2 sr2[4], si2[4];
  const float* sp = Sin + (size_t)grp * 64 + gl * 16;
  #pragma unroll
  for (int j = 0; j < 4; ++j) {
    sr2[j][0] = sp[4*j];   sr2[j][1] = sp[4*j+2];
    si2[j][0] = sp[4*j+1]; si2[j][1] = sp[4*j+3];
  }
  size_t base = (size_t)p * LL + (size_t)g * LC;
  const float* up = U + base;
  float* yp = YB + base;

#define QB(J2, CMP, ACC) { \
    float ubv = qbcast<(J2)*0x55>(u4.CMP); \
    float c = out4(sr2, si2, cr2, nci2); \
    upd4(sr2, si2, wr2, wi2, nwi2, ubv); \
    c = qadd<0xB1>(c); c = qadd<0x4E>(c); \
    ACC = (gl == (J2)) ? c : ACC; }
  for (int ii = NIT - 1; ii >= 0; --ii) {
    float4 u4 = ((const float4*)(up + 16 * ii))[gl];
    float a0 = 0.f, a1 = 0.f, a2 = 0.f, a3 = 0.f;
    QB(3,w,a3) QB(3,z,a2) QB(3,y,a1) QB(3,x,a0)
    QB(2,w,a3) QB(2,z,a2) QB(2,y,a1) QB(2,x,a0)
    QB(1,w,a3) QB(1,z,a2) QB(1,y,a1) QB(1,x,a0)
    QB(0,w,a3) QB(0,z,a2) QB(0,y,a1) QB(0,x,a0)
    float4 o4; o4.x = a0; o4.y = a1; o4.z = a2; o4.w = a3;
    ((float4*)(yp + 16 * ii))[gl] = o4;
  }
#undef QB
}

// ---------------------------------------------------------------------------
// Pass C forward: combine y_f + y_b + D*u, gelu, write over U in place.
// ---------------------------------------------------------------------------
__device__ __forceinline__ float gelu_t(float y) {
  float y2 = y * y;
  float arg = 1.5957691216f * fmaf(0.044715f * y2, y, y);
  return y / (1.f + __expf(-arg));
}
__global__ __launch_bounds__(256) void scanC_fwd(float* __restrict__ U,
                                                 const float* __restrict__ P,
                                                 const float* __restrict__ Sin,
                                                 const float* __restrict__ YB,
                                                 const float* __restrict__ Dv) {
  int tid = threadIdx.x;
  int gl  = tid & 3;
  int grp = (blockIdx.x << 6) | (tid >> 2);
  int p = grp >> 4, g = grp & (NG - 1), h = p & (HH - 1);
  const float* Pb = P + h * NHD + gl * 8;
  f32x2 wr2[4], wi2[4], nwi2[4], cr2[4], nci2[4];
  #pragma unroll
  for (int j = 0; j < 4; ++j) {
    wr2[j]  = ((const f32x2*)Pb)[j];
    wi2[j]  = ((const f32x2*)(Pb + HN))[j];
    nwi2[j] = -wi2[j];
    cr2[j]  = ((const f32x2*)(Pb + 2*HN))[j];
    nci2[j] = -((const f32x2*)(Pb + 3*HN))[j];
  }
  float dh = Dv[h];
  f32x2 sr2[4], si2[4];
  const float* sp = Sin + (size_t)grp * 64 + gl * 16;
  #pragma unroll
  for (int j = 0; j < 4; ++j) {
    sr2[j][0] = sp[4*j];   sr2[j][1] = sp[4*j+2];
    si2[j][0] = sp[4*j+1]; si2[j][1] = sp[4*j+3];
  }
  size_t base = (size_t)p * LL + (size_t)g * LC;
  float* up = U + base;
  const float* ybp = YB + base;

#define QF(J2, CMP, ACC) { \
    float ubv = qbcast<(J2)*0x55>(u4.CMP); \
    upd4(sr2, si2, wr2, wi2, nwi2, ubv); \
    float c = out4(sr2, si2, cr2, nci2); \
    c = qadd<0xB1>(c); c = qadd<0x4E>(c); \
    ACC = (gl == (J2)) ? c : ACC; }
  for (int ii = 0; ii < NIT; ++ii) {
    float4 u4  = ((const float4*)(up + 16 * ii))[gl];
    float4 yb4 = ((const float4*)(ybp + 16 * ii))[gl];
    float a0 = 0.f, a1 = 0.f, a2 = 0.f, a3 = 0.f;
    QF(0,x,a0) QF(0,y,a1) QF(0,z,a2) QF(0,w,a3)
    QF(1,x,a0) QF(1,y,a1) QF(1,z,a2) QF(1,w,a3)
    QF(2,x,a0) QF(2,y,a1) QF(2,z,a2) QF(2,w,a3)
    QF(3,x,a0) QF(3,y,a1) QF(3,z,a2) QF(3,w,a3)
    float4 o4;
    o4.x = gelu_t(a0 + yb4.x + dh * u4.x);
    o4.y = gelu_t(a1 + yb4.y + dh * u4.y);
    o4.z = gelu_t(a2 + yb4.z + dh * u4.z);
    o4.w = gelu_t(a3 + yb4.w + dh * u4.w);
    ((float4*)(up + 16 * ii))[gl] = o4;
  }
#undef QF
}

// ---------------------------------------------------------------------------
// MFMA GEMM + GLU, pure bf16, direct-from-global (R3 memory structure).
// Block: 1024 thr (16 waves), BN=128. Wave w owns o-rows {w*16..+16} (z1)
// and {256+w*16..+16} (z2) so GLU pairs are lane-local.
// ---------------------------------------------------------------------------
__global__ __launch_bounds__(1024, 4) void gemm_mfma(
    const unsigned short* __restrict__ Wb,
    const unsigned short* __restrict__ Yb,
    const float* __restrict__ bvec, float* __restrict__ out) {
  int tid  = threadIdx.x;
  int w    = tid >> 6;
  int lane = tid & 63;
  int ln = lane & 15, lg = lane >> 4;
  int b  = blockIdx.x >> 6;
  int l0 = (blockIdx.x & 63) << 7;

  const short8* W8 = (const short8*)Wb;
  const short8* Y8 = (const short8*)Yb;

  floatx4 acc[2][8];
  #pragma unroll
  for (int m = 0; m < 2; ++m)
    #pragma unroll
    for (int n = 0; n < 8; ++n) acc[m][n] = (floatx4){0.f, 0.f, 0.f, 0.f};

  size_t ybase = ((size_t)(b * LL + l0) + ln) * 32 + lg;  // short8 units (row=32)

  #pragma unroll
  for (int ks = 0; ks < 8; ++ks) {
    short8 Bf[8];
    size_t yb = ybase + ks * 4;
    #pragma unroll
    for (int nf = 0; nf < 8; ++nf)
      Bf[nf] = Y8[yb + (size_t)nf * 16 * 32];
    #pragma unroll
    for (int mm = 0; mm < 2; ++mm) {
      int orow = (mm << 8) + w * 16 + ln;
      short8 Af = W8[(size_t)orow * 32 + ks * 4 + lg];
      #pragma unroll
      for (int nf = 0; nf < 8; ++nf)
        acc[mm][nf] = __builtin_amdgcn_mfma_f32_16x16x32_bf16(Af, Bf[nf], acc[mm][nf], 0, 0, 0);
    }
  }

  // epilogue: bias + GLU. D layout: col=lane&15, row=(lane>>4)*4+reg.
  int obase = w * 16 + lg * 4;
  #pragma unroll
  for (int r = 0; r < 4; ++r) {
    int o = obase + r;
    float b0 = bvec[o];
    float b1 = bvec[HH + o];
    float* op = out + ((size_t)(b * HH + o)) * LL + l0 + ln;
    #pragma unroll
    for (int nf = 0; nf < 8; ++nf) {
      float z1 = acc[0][nf][r] + b0;
      float z2 = acc[1][nf][r] + b1;
      op[nf * 16] = z1 / (1.f + __expf(-z2));
    }
  }
}

// ---------------------------------------------------------------------------
// Fallback f32 GEMM (used only if ws too small for the MFMA path)
// ---------------------------------------------------------------------------
__global__ __launch_bounds__(256, 4) void gemm_kernel(const float* __restrict__ Y,
                                                      const float* __restrict__ WT,
                                                      const float* __restrict__ bvec,
                                                      float* __restrict__ out) {
  __shared__ float ytile[HH][36];
  int tid = threadIdx.x;
  int b   = blockIdx.x >> 8;
  int l0  = (blockIdx.x & 255) << 5;
  const float* yrow = Y + ((size_t)b * HH + tid) * LL + l0;
  float4* drow = (float4*)&ytile[tid][0];
  #pragma unroll
  for (int jj = 0; jj < 8; ++jj)
    drow[jj] = ((const float4*)yrow)[jj];
  __syncthreads();
  float acc0[32], acc1[32];
  #pragma unroll
  for (int j = 0; j < 32; ++j) { acc0[j] = 0.f; acc1[j] = 0.f; }
  #pragma unroll 2
  for (int h = 0; h < HH; ++h) {
    float w0 = WT[h * 512 + tid];
    float w1 = WT[h * 512 + 256 + tid];
    const float4* r = (const float4*)&ytile[h][0];
    #pragma unroll
    for (int jj = 0; jj < 8; ++jj) {
      float4 y4 = r[jj];
      acc0[4*jj+0] = fmaf(w0, y4.x, acc0[4*jj+0]);
      acc0[4*jj+1] = fmaf(w0, y4.y, acc0[4*jj+1]);
      acc0[4*jj+2] = fmaf(w0, y4.z, acc0[4*jj+2]);
      acc0[4*jj+3] = fmaf(w0, y4.w, acc0[4*jj+3]);
      acc1[4*jj+0] = fmaf(w1, y4.x, acc1[4*jj+0]);
      acc1[4*jj+1] = fmaf(w1, y4.y, acc1[4*jj+1]);
      acc1[4*jj+2] = fmaf(w1, y4.z, acc1[4*jj+2]);
      acc1[4*jj+3] = fmaf(w1, y4.w, acc1[4*jj+3]);
    }
  }
  float b0 = bvec[tid], b1 = bvec[HH + tid];
  float* orow = out + ((size_t)b * HH + tid) * LL + l0;
  #pragma unroll
  for (int j = 0; j < 32; ++j) {
    float z1 = acc0[j] + b0;
    float z2 = acc1[j] + b1;
    orow[j] = z1 * (1.0f / (1.0f + __expf(-z2)));
  }
}

// ---------------------------------------------------------------------------
extern "C" void kernel_launch(void* const* d_in, const int* in_sizes, int n_in,
                              void* d_out, int out_size, void* d_ws, size_t ws_size,
                              hipStream_t stream) {
  const float* x      = (const float*)d_in[0];
  const float* log_dt = (const float*)d_in[1];
  const float* A_real = (const float*)d_in[2];
  const float* A_imag = (const float*)d_in[3];
  const float* C_real = (const float*)d_in[4];
  const float* C_imag = (const float*)d_in[5];
  const float* Dv     = (const float*)d_in[6];
  const float* W      = (const float*)d_in[7];
  const float* bvec   = (const float*)d_in[8];
  float* out = (float*)d_out;

  char* ws = (char*)d_ws;
  float*          P   = (float*)ws;                       // 256 KB
  float*          WT  = (float*)(ws + 262144);            // 512 KB (fallback)
  unsigned short* Wb  = (unsigned short*)(ws + 786432);   // 256 KB
  size_t OFF_U   = (size_t)2 << 20;
  size_t U_BYTES = (size_t)BH * LL * 4;                   // 128 MB
  size_t S_BYTES = (size_t)BH * NG * 64 * 4;              // 16 MB each
  size_t OFF_SF  = OFF_U + U_BYTES;
  size_t OFF_SB  = OFF_SF + S_BYTES;
  size_t OFF_YH  = OFF_SB + S_BYTES;
  size_t Y_BYTES = (size_t)BB * LL * HH * 2;              // 64 MB
  size_t NEED    = OFF_YH + Y_BYTES;                      // ~226 MB
  float* U  = (float*)(ws + OFF_U);
  float* SF = (float*)(ws + OFF_SF);
  float* SB = (float*)(ws + OFF_SB);
  unsigned short* Yb = (unsigned short*)(ws + OFF_YH);

  bool mfma_path = (ws_size >= NEED);

  precomp_kernel<<<HN / 256, 256, 0, stream>>>(log_dt, A_real, A_imag, C_real, C_imag, P);
  if (mfma_path)
    wt_bf16_kernel<<<512, 256, 0, stream>>>(W, Wb);
  else
    wt_kernel<<<512, 256, 0, stream>>>(W, WT);
  transpose_kernel<<<dim3(BH / 32, LL / 32), dim3(32, 8), 0, stream>>>(x, U);
  scanA<<<(BH * NG) / 64, 256, 0, stream>>>(U, P, SF, SB);
  scanB<<<(BH * NHD) / 256, 256, 0, stream>>>(P, SF, SB);
  scanC_bwd<<<(BH * NG) / 64, 256, 0, stream>>>(U, P, SB, (float*)d_out);
  scanC_fwd<<<(BH * NG) / 64, 256, 0, stream>>>(U, P, SF, (const float*)d_out, Dv);
  if (mfma_path) {
    convT_kernel<<<dim3(BH / 32, LL / 32), dim3(32, 8), 0, stream>>>(U, Yb);
    gemm_mfma<<<BB * (LL / 128), 1024, 0, stream>>>(Wb, Yb, bvec, out);
  } else {
    gemm_kernel<<<BB * (LL / 32), 256, 0, stream>>>(U, WT, bvec, out);
  }
}

// Round 7
// 783.499 us; speedup vs baseline: 1.1796x; 1.0565x over previous
//
#include <hip/hip_runtime.h>
#include <hip/hip_bf16.h>
#include <math.h>

#define HH  256      // d_model
#define NHD 32       // state halves
#define LL  8192     // sequence length
#define BB  16       // batch
#define HN  (HH*NHD) // 8192
#define BH  (BB*HH)  // 4096
#define LC  256      // chunk length
#define NG  (LL/LC)  // 32 chunks per row
#define NIT (LC/16)  // 16 sub-iters per chunk
#define NINST (BB*NG) // 512 chunk instances per h

typedef __attribute__((ext_vector_type(8))) short short8;
typedef __attribute__((ext_vector_type(4))) float floatx4;
typedef __attribute__((ext_vector_type(2))) float f32x2;

// ---------------------------------------------------------------------------
// packed f32 math (issue-rate-neutral on gfx950 per R3 A/B; kept: fewer insts)
// ---------------------------------------------------------------------------
__device__ __forceinline__ f32x2 pk_fma(f32x2 a, f32x2 b, f32x2 c) {
  f32x2 d;
  asm("v_pk_fma_f32 %0, %1, %2, %3" : "=v"(d) : "v"(a), "v"(b), "v"(c));
  return d;
}
__device__ __forceinline__ f32x2 pk_mul(f32x2 a, f32x2 b) {
  f32x2 d;
  asm("v_pk_mul_f32 %0, %1, %2" : "=v"(d) : "v"(a), "v"(b));
  return d;
}
__device__ __forceinline__ void pk_fma_acc(f32x2& c, f32x2 a, f32x2 b) {
  asm("v_pk_fma_f32 %0, %1, %2, %0" : "+v"(c) : "v"(a), "v"(b));
}

__device__ __forceinline__ unsigned short f2bf(float f) {
  unsigned u = __float_as_uint(f);
  unsigned r = (u + 0x7FFF + ((u >> 16) & 1)) >> 16;
  return (unsigned short)r;
}
__device__ __forceinline__ unsigned packbf2(float a, float b) {
  return (unsigned)f2bf(a) | ((unsigned)f2bf(b) << 16);
}

// ---------------------------------------------------------------------------
// Param precompute. P[k*HN + h*NHD + n]:
// 0=wr 1=wi 2=c0r 3=c0i 4=c1r 5=c1i 6=wLr 7=wLi   (wL = w^LC)
// ---------------------------------------------------------------------------
__global__ void precomp_kernel(const float* __restrict__ log_dt,
                               const float* __restrict__ A_real,
                               const float* __restrict__ A_imag,
                               const float* __restrict__ C_real,
                               const float* __restrict__ C_imag,
                               float* __restrict__ P) {
  int i = blockIdx.x * blockDim.x + threadIdx.x;
  if (i >= HN) return;
  int h = i >> 5;
  double dt  = exp((double)log_dt[h]);
  double Are = -exp((double)A_real[i]);
  double Aim = (double)A_imag[i];
  double ar = Are * dt, ai = Aim * dt;
  double ea = exp(ar);
  double wr = ea * cos(ai), wi = ea * sin(ai);
  double em_r = wr - 1.0, em_i = wi;
  double den = Are * Are + Aim * Aim;
  double rr = (em_r * Are + em_i * Aim) / den;
  double ri = (em_i * Are - em_r * Aim) / den;
  P[0*HN + i] = (float)wr;
  P[1*HN + i] = (float)wi;
  {
    double cr = (double)C_real[i], ci = (double)C_imag[i];
    P[2*HN + i] = (float)(2.0 * (cr * rr - ci * ri));
    P[3*HN + i] = (float)(2.0 * (cr * ri + ci * rr));
  }
  {
    double cr = (double)C_real[HN + i], ci = (double)C_imag[HN + i];
    P[4*HN + i] = (float)(2.0 * (cr * rr - ci * ri));
    P[5*HN + i] = (float)(2.0 * (cr * ri + ci * rr));
  }
  {
    double arL = ar * (double)LC, aiL = ai * (double)LC;
    double eaL = exp(arL);
    P[6*HN + i] = (float)(eaL * cos(aiL));
    P[7*HN + i] = (float)(eaL * sin(aiL));
  }
}

// W (512,256) row-major -> bf16 (RNE), same layout
__global__ void wt_bf16_kernel(const float* __restrict__ W,
                               unsigned short* __restrict__ Wb) {
  int idx = blockIdx.x * 256 + threadIdx.x;
  Wb[idx] = f2bf(W[idx]);
}

// ---------------------------------------------------------------------------
// x (L, B*H) -> U (B*H, L)  tiled transpose
// ---------------------------------------------------------------------------
__global__ void transpose_kernel(const float* __restrict__ x, float* __restrict__ U) {
  __shared__ float tile[32][33];
  int gx = blockIdx.x * 32;
  int gy = blockIdx.y * 32;
  int tx = threadIdx.x, ty = threadIdx.y;
  #pragma unroll
  for (int k2 = 0; k2 < 4; ++k2)
    tile[ty + 8*k2][tx] = x[(size_t)(gy + ty + 8*k2) * BH + gx + tx];
  __syncthreads();
  #pragma unroll
  for (int k2 = 0; k2 < 4; ++k2)
    U[(size_t)(gx + ty + 8*k2) * LL + gy + tx] = tile[tx][ty + 8*k2];
}

// ---------------------------------------------------------------------------
// U (B*H, L) f32 -> Yb (B*L, H) bf16 (k-contiguous rows for MFMA B-frags)
// ---------------------------------------------------------------------------
__global__ void convT_kernel(const float* __restrict__ U,
                             unsigned short* __restrict__ Yb) {
  __shared__ float tile[32][33];
  int pb = blockIdx.x * 32;
  int lb = blockIdx.y * 32;
  int tx = threadIdx.x, ty = threadIdx.y;
  #pragma unroll
  for (int k2 = 0; k2 < 4; ++k2)
    tile[ty + 8*k2][tx] = U[(size_t)(pb + ty + 8*k2) * LL + lb + tx];
  __syncthreads();
  int b = pb >> 8, h0 = pb & 255;
  #pragma unroll
  for (int k2 = 0; k2 < 4; ++k2) {
    int r = ty + 8*k2;
    size_t o = (size_t)(b * LL + lb + r) * HH + h0 + tx;
    Yb[o] = f2bf(tile[tx][r]);
  }
}

// ---------------------------------------------------------------------------
// quad (4-lane) DPP helpers
// ---------------------------------------------------------------------------
template<int CTRL>
__device__ __forceinline__ float qbcast(float v) {
  int t = __builtin_amdgcn_update_dpp(0, __float_as_int(v), CTRL, 0xF, 0xF, true);
  return __int_as_float(t);
}
template<int CTRL>
__device__ __forceinline__ float qadd(float v) {
  int t = __builtin_amdgcn_update_dpp(0, __float_as_int(v), CTRL, 0xF, 0xF, true);
  return v + __int_as_float(t);
}

// ---------------------------------------------------------------------------
// packed step primitives: 8 complex states per lane as 4 pairs
// ---------------------------------------------------------------------------
__device__ __forceinline__ void upd4(f32x2 (&sr)[4], f32x2 (&si)[4],
                                     const f32x2 (&wr)[4], const f32x2 (&wi)[4],
                                     const f32x2 (&nwi)[4], float ub) {
  f32x2 u2; u2[0] = ub; u2[1] = ub;
  #pragma unroll
  for (int j = 0; j < 4; ++j) {
    f32x2 t   = pk_fma(wr[j], sr[j], u2);
    f32x2 m   = pk_mul(wr[j], si[j]);
    f32x2 srn = pk_fma(nwi[j], si[j], t);
    si[j] = pk_fma(wi[j], sr[j], m);
    sr[j] = srn;
  }
}
__device__ __forceinline__ float out4(const f32x2 (&sr)[4], const f32x2 (&si)[4],
                                      const f32x2 (&cr)[4], const f32x2 (&nci)[4]) {
  f32x2 a = pk_mul(cr[0], sr[0]);
  f32x2 b = pk_mul(nci[0], si[0]);
  pk_fma_acc(a, cr[1], sr[1]);  pk_fma_acc(b, nci[1], si[1]);
  pk_fma_acc(a, cr[2], sr[2]);  pk_fma_acc(b, nci[2], si[2]);
  pk_fma_acc(a, cr[3], sr[3]);  pk_fma_acc(b, nci[3], si[3]);
  return (a[0] + a[1]) + (b[0] + b[1]);
}

// ---------------------------------------------------------------------------
// Local backward scan (zero init): writes y_b partials and chunk-final states.
// Output at t uses state BEFORE absorbing u[t] (= local sB[t+1]).
// ---------------------------------------------------------------------------
__global__ __launch_bounds__(256) void scanL_bwd(const float* __restrict__ U,
                                                 const float* __restrict__ P,
                                                 float* __restrict__ YB,
                                                 float* __restrict__ SB) {
  int tid = threadIdx.x;
  int gl  = tid & 3;
  int grp = (blockIdx.x << 6) | (tid >> 2);
  int p = grp >> 5, g = grp & (NG - 1), h = p & (HH - 1);
  const float* Pb = P + h * NHD + gl * 8;
  f32x2 wr2[4], wi2[4], nwi2[4], cr2[4], nci2[4];
  #pragma unroll
  for (int j = 0; j < 4; ++j) {
    wr2[j]  = ((const f32x2*)Pb)[j];
    wi2[j]  = ((const f32x2*)(Pb + HN))[j];
    nwi2[j] = -wi2[j];
    cr2[j]  = ((const f32x2*)(Pb + 4*HN))[j];
    nci2[j] = -((const f32x2*)(Pb + 5*HN))[j];
  }
  f32x2 sr2[4], si2[4];
  #pragma unroll
  for (int j = 0; j < 4; ++j) { sr2[j] = (f32x2){0.f,0.f}; si2[j] = (f32x2){0.f,0.f}; }
  size_t base = (size_t)p * LL + (size_t)g * LC;
  const float* up = U + base;
  float* yp = YB + base;

#define QB(J2, CMP, ACC) { \
    float ubv = qbcast<(J2)*0x55>(u4.CMP); \
    float c = out4(sr2, si2, cr2, nci2); \
    upd4(sr2, si2, wr2, wi2, nwi2, ubv); \
    c = qadd<0xB1>(c); c = qadd<0x4E>(c); \
    ACC = (gl == (J2)) ? c : ACC; }
  for (int ii = NIT - 1; ii >= 0; --ii) {
    float4 u4 = ((const float4*)(up + 16 * ii))[gl];
    float a0 = 0.f, a1 = 0.f, a2 = 0.f, a3 = 0.f;
    QB(3,w,a3) QB(3,z,a2) QB(3,y,a1) QB(3,x,a0)
    QB(2,w,a3) QB(2,z,a2) QB(2,y,a1) QB(2,x,a0)
    QB(1,w,a3) QB(1,z,a2) QB(1,y,a1) QB(1,x,a0)
    QB(0,w,a3) QB(0,z,a2) QB(0,y,a1) QB(0,x,a0)
    float4 o4; o4.x = a0; o4.y = a1; o4.z = a2; o4.w = a3;
    ((float4*)(yp + 16 * ii))[gl] = o4;
  }
#undef QB
  float4* ob = (float4*)(SB + (size_t)grp * 64 + gl * 16);
  #pragma unroll
  for (int j = 0; j < 4; ++j) {
    float4 v; v.x = sr2[j][0]; v.y = si2[j][0]; v.z = sr2[j][1]; v.w = si2[j][1];
    ob[j] = v;
  }
}

// ---------------------------------------------------------------------------
// Local forward scan (zero init): S = y_f_loc + y_b_loc + D*u written over U
// (no gelu here), plus chunk-final states.
// ---------------------------------------------------------------------------
__global__ __launch_bounds__(256) void scanL_fwd(float* __restrict__ U,
                                                 const float* __restrict__ P,
                                                 const float* __restrict__ YB,
                                                 const float* __restrict__ Dv,
                                                 float* __restrict__ SF) {
  int tid = threadIdx.x;
  int gl  = tid & 3;
  int grp = (blockIdx.x << 6) | (tid >> 2);
  int p = grp >> 5, g = grp & (NG - 1), h = p & (HH - 1);
  const float* Pb = P + h * NHD + gl * 8;
  f32x2 wr2[4], wi2[4], nwi2[4], cr2[4], nci2[4];
  #pragma unroll
  for (int j = 0; j < 4; ++j) {
    wr2[j]  = ((const f32x2*)Pb)[j];
    wi2[j]  = ((const f32x2*)(Pb + HN))[j];
    nwi2[j] = -wi2[j];
    cr2[j]  = ((const f32x2*)(Pb + 2*HN))[j];
    nci2[j] = -((const f32x2*)(Pb + 3*HN))[j];
  }
  float dh = Dv[h];
  f32x2 sr2[4], si2[4];
  #pragma unroll
  for (int j = 0; j < 4; ++j) { sr2[j] = (f32x2){0.f,0.f}; si2[j] = (f32x2){0.f,0.f}; }
  size_t base = (size_t)p * LL + (size_t)g * LC;
  float* up = U + base;
  const float* ybp = YB + base;

#define QF(J2, CMP, ACC) { \
    float ubv = qbcast<(J2)*0x55>(u4.CMP); \
    upd4(sr2, si2, wr2, wi2, nwi2, ubv); \
    float c = out4(sr2, si2, cr2, nci2); \
    c = qadd<0xB1>(c); c = qadd<0x4E>(c); \
    ACC = (gl == (J2)) ? c : ACC; }
  for (int ii = 0; ii < NIT; ++ii) {
    float4 u4  = ((const float4*)(up + 16 * ii))[gl];
    float4 yb4 = ((const float4*)(ybp + 16 * ii))[gl];
    float a0 = 0.f, a1 = 0.f, a2 = 0.f, a3 = 0.f;
    QF(0,x,a0) QF(0,y,a1) QF(0,z,a2) QF(0,w,a3)
    QF(1,x,a0) QF(1,y,a1) QF(1,z,a2) QF(1,w,a3)
    QF(2,x,a0) QF(2,y,a1) QF(2,z,a2) QF(2,w,a3)
    QF(3,x,a0) QF(3,y,a1) QF(3,z,a2) QF(3,w,a3)
    float4 o4;
    o4.x = a0 + yb4.x + dh * u4.x;
    o4.y = a1 + yb4.y + dh * u4.y;
    o4.z = a2 + yb4.z + dh * u4.z;
    o4.w = a3 + yb4.w + dh * u4.w;
    ((float4*)(up + 16 * ii))[gl] = o4;
  }
#undef QF
  float4* of = (float4*)(SF + (size_t)grp * 64 + gl * 16);
  #pragma unroll
  for (int j = 0; j < 4; ++j) {
    float4 v; v.x = sr2[j][0]; v.y = si2[j][0]; v.z = sr2[j][1]; v.w = si2[j][1];
    of[j] = v;
  }
}

// ---------------------------------------------------------------------------
// Cross-chunk scan: local finals -> incoming states per chunk, packed bf16
// Sc[h][inst=b*NG+g][k]: k<64 fwd (Re,Im interleaved), k>=64 bwd.
// ---------------------------------------------------------------------------
__global__ __launch_bounds__(256) void scanB_kernel(const float* __restrict__ P,
                                                    const float* __restrict__ SF,
                                                    const float* __restrict__ SB,
                                                    unsigned short* __restrict__ Sc) {
  int t = blockIdx.x * 256 + threadIdx.x;
  if (t >= BH * NHD) return;
  int p = t >> 5, n = t & 31, h = p & (HH - 1), b = p >> 8;
  float wlr = P[6*HN + h*NHD + n], wli = P[7*HN + h*NHD + n];
  unsigned* scp = (unsigned*)(Sc + ((size_t)(h * BB + b) * NG) * 128);
  {
    const float* f = SF + (size_t)p * NG * 64 + 2 * n;
    float ar = 0.f, ai = 0.f;
    for (int g = 0; g < NG; ++g) {
      scp[g * 64 + n] = packbf2(ar, ai);
      float lr = f[g*64], li = f[g*64+1];
      float nr = lr + wlr * ar - wli * ai;
      float ni = li + wlr * ai + wli * ar;
      ar = nr; ai = ni;
    }
  }
  {
    const float* bp = SB + (size_t)p * NG * 64 + 2 * n;
    float ar = 0.f, ai = 0.f;
    for (int g = NG - 1; g >= 0; --g) {
      scp[g * 64 + 32 + n] = packbf2(ar, ai);
      float lr = bp[g*64], li = bp[g*64+1];
      float nr = lr + wlr * ar - wli * ai;
      float ni = li + wlr * ai + wli * ar;
      ar = nr; ai = ni;
    }
  }
}

// ---------------------------------------------------------------------------
// E-table: E[h][t][k] bf16. k=2n: Re(c0*w^(t+1)), k=2n+1: -Im(c0*w^(t+1));
// k=64+2n: Re(c1*w^(LC-1-t)), k=64+2n+1: -Im(...).
// ---------------------------------------------------------------------------
__global__ __launch_bounds__(256) void eprep_kernel(const float* __restrict__ P,
                                                    unsigned short* __restrict__ E) {
  int i = blockIdx.x * 256 + threadIdx.x;   // i = h*32 + n
  if (i >= HN) return;
  int n = i & 31, h = i >> 5;
  float wr = P[i], wi = P[HN + i];
  unsigned* ep = (unsigned*)E;              // uint row stride = 64 per t
  {
    float cr = P[2*HN + i], ci = P[3*HN + i];
    float er = cr * wr - ci * wi;
    float ei = cr * wi + ci * wr;
    for (int t = 0; t < LC; ++t) {
      ep[((size_t)h * LC + t) * 64 + n] = packbf2(er, -ei);
      float nr = er * wr - ei * wi;
      float ni = er * wi + ei * wr;
      er = nr; ei = ni;
    }
  }
  {
    float er = P[4*HN + i], ei = P[5*HN + i];   // c1 * w^0
    for (int t = LC - 1; t >= 0; --t) {
      ep[((size_t)h * LC + t) * 64 + 32 + n] = packbf2(er, -ei);
      float nr = er * wr - ei * wi;
      float ni = er * wi + ei * wr;
      er = nr; ei = ni;
    }
  }
}

// ---------------------------------------------------------------------------
// Correction + gelu (in place on U): y = gelu(S + E[h] . Sc[h][inst]).
// Block: 4 waves; wave covers 16 t x 16 inst for one h. K=128 (fwd+bwd).
// ---------------------------------------------------------------------------
__device__ __forceinline__ float gelu_t(float y) {
  float y2 = y * y;
  float arg = 1.5957691216f * fmaf(0.044715f * y2, y, y);
  return y / (1.f + __expf(-arg));
}
__global__ __launch_bounds__(256) void corr_kernel(const unsigned short* __restrict__ E,
                                                   const unsigned short* __restrict__ Sc,
                                                   float* __restrict__ U) {
  int tid  = threadIdx.x;
  int w    = tid >> 6;
  int lane = tid & 63;
  int ln = lane & 15, lg = lane >> 4;
  int bid = blockIdx.x;
  int h     = bid >> 7;          // 4 ttiles * 32 itiles = 128 blocks per h
  int ttile = (bid >> 5) & 3;
  int itile = bid & 31;
  int t0 = ttile * 64 + w * 16;
  int i0 = itile * 16;

  const short8* E8 = (const short8*)E;    // 16B units; row = 16 units
  const short8* S8 = (const short8*)Sc;
  size_t arow = ((size_t)h * LC + t0 + ln) * 16 + lg;
  size_t brow = ((size_t)h * NINST + i0 + ln) * 16 + lg;

  floatx4 acc = (floatx4){0.f, 0.f, 0.f, 0.f};
  #pragma unroll
  for (int ks = 0; ks < 4; ++ks) {
    short8 Af = E8[arow + ks * 4];
    short8 Bf = S8[brow + ks * 4];
    acc = __builtin_amdgcn_mfma_f32_16x16x32_bf16(Af, Bf, acc, 0, 0, 0);
  }

  int inst = i0 + ln;
  int b = inst >> 5, g = inst & 31;
  float* sp = U + ((size_t)(b * HH + h)) * LL + (size_t)g * LC + t0 + lg * 4;
  float4 s4 = *(const float4*)sp;
  s4.x = gelu_t(s4.x + acc[0]);
  s4.y = gelu_t(s4.y + acc[1]);
  s4.z = gelu_t(s4.z + acc[2]);
  s4.w = gelu_t(s4.w + acc[3]);
  *(float4*)sp = s4;
}

// ---------------------------------------------------------------------------
// MFMA GEMM + GLU, pure bf16, direct-from-global (R5 structure, unchanged).
// ---------------------------------------------------------------------------
__global__ __launch_bounds__(1024, 4) void gemm_mfma(
    const unsigned short* __restrict__ Wb,
    const unsigned short* __restrict__ Yb,
    const float* __restrict__ bvec, float* __restrict__ out) {
  int tid  = threadIdx.x;
  int w    = tid >> 6;
  int lane = tid & 63;
  int ln = lane & 15, lg = lane >> 4;
  int b  = blockIdx.x >> 6;
  int l0 = (blockIdx.x & 63) << 7;

  const short8* W8 = (const short8*)Wb;
  const short8* Y8 = (const short8*)Yb;

  floatx4 acc[2][8];
  #pragma unroll
  for (int m = 0; m < 2; ++m)
    #pragma unroll
    for (int n = 0; n < 8; ++n) acc[m][n] = (floatx4){0.f, 0.f, 0.f, 0.f};

  size_t ybase = ((size_t)(b * LL + l0) + ln) * 32 + lg;

  #pragma unroll
  for (int ks = 0; ks < 8; ++ks) {
    short8 Bf[8];
    size_t yb = ybase + ks * 4;
    #pragma unroll
    for (int nf = 0; nf < 8; ++nf)
      Bf[nf] = Y8[yb + (size_t)nf * 16 * 32];
    #pragma unroll
    for (int mm = 0; mm < 2; ++mm) {
      int orow = (mm << 8) + w * 16 + ln;
      short8 Af = W8[(size_t)orow * 32 + ks * 4 + lg];
      #pragma unroll
      for (int nf = 0; nf < 8; ++nf)
        acc[mm][nf] = __builtin_amdgcn_mfma_f32_16x16x32_bf16(Af, Bf[nf], acc[mm][nf], 0, 0, 0);
    }
  }

  int obase = w * 16 + lg * 4;
  #pragma unroll
  for (int r = 0; r < 4; ++r) {
    int o = obase + r;
    float b0 = bvec[o];
    float b1 = bvec[HH + o];
    float* op = out + ((size_t)(b * HH + o)) * LL + l0 + ln;
    #pragma unroll
    for (int nf = 0; nf < 8; ++nf) {
      float z1 = acc[0][nf][r] + b0;
      float z2 = acc[1][nf][r] + b1;
      op[nf * 16] = z1 / (1.f + __expf(-z2));
    }
  }
}

// ---------------------------------------------------------------------------
extern "C" void kernel_launch(void* const* d_in, const int* in_sizes, int n_in,
                              void* d_out, int out_size, void* d_ws, size_t ws_size,
                              hipStream_t stream) {
  const float* x      = (const float*)d_in[0];
  const float* log_dt = (const float*)d_in[1];
  const float* A_real = (const float*)d_in[2];
  const float* A_imag = (const float*)d_in[3];
  const float* C_real = (const float*)d_in[4];
  const float* C_imag = (const float*)d_in[5];
  const float* Dv     = (const float*)d_in[6];
  const float* W      = (const float*)d_in[7];
  const float* bvec   = (const float*)d_in[8];
  float* out = (float*)d_out;

  char* ws = (char*)d_ws;
  float*          P  = (float*)ws;                          // 256 KB
  unsigned short* Wb = (unsigned short*)(ws + 262144);      // 256 KB
  size_t OFF_U  = (size_t)2 << 20;                          // 2 MB
  size_t U_BY   = (size_t)BH * LL * 4;                      // 128 MB
  size_t OFF_SC = OFF_U + U_BY;
  size_t SC_BY  = (size_t)HH * NINST * 128 * 2;             // 32 MB
  size_t OFF_E  = OFF_SC + SC_BY;
  size_t E_BY   = (size_t)HH * LC * 128 * 2;                // 16 MB
  size_t OFF_SF = OFF_E + E_BY;
  size_t SFB    = (size_t)BH * NG * 64 * 4;                 // 32 MB
  size_t OFF_SB = OFF_SF + SFB;                             // +32 MB
  size_t OFF_YB = OFF_SF;                                   // Yb aliases SF+SB (64 MB)
  float* U  = (float*)(ws + OFF_U);
  unsigned short* Sc = (unsigned short*)(ws + OFF_SC);
  unsigned short* E  = (unsigned short*)(ws + OFF_E);
  float* SF = (float*)(ws + OFF_SF);
  float* SB = (float*)(ws + OFF_SB);
  unsigned short* Yb = (unsigned short*)(ws + OFF_YB);

  precomp_kernel<<<HN / 256, 256, 0, stream>>>(log_dt, A_real, A_imag, C_real, C_imag, P);
  wt_bf16_kernel<<<512, 256, 0, stream>>>(W, Wb);
  eprep_kernel<<<HN / 256, 256, 0, stream>>>(P, E);
  transpose_kernel<<<dim3(BH / 32, LL / 32), dim3(32, 8), 0, stream>>>(x, U);
  scanL_bwd<<<(BH * NG) / 64, 256, 0, stream>>>(U, P, (float*)d_out, SB);
  scanL_fwd<<<(BH * NG) / 64, 256, 0, stream>>>(U, P, (const float*)d_out, Dv, SF);
  scanB_kernel<<<(BH * NHD) / 256, 256, 0, stream>>>(P, SF, SB, Sc);
  corr_kernel<<<HH * 128, 256, 0, stream>>>(E, Sc, U);
  convT_kernel<<<dim3(BH / 32, LL / 32), dim3(32, 8), 0, stream>>>(U, Yb);
  gemm_mfma<<<BB * (LL / 128), 1024, 0, stream>>>(Wb, Yb, bvec, out);
}

// Round 8
// 706.399 us; speedup vs baseline: 1.3083x; 1.1091x over previous
//
#include <hip/hip_runtime.h>
#include <hip/hip_bf16.h>
#include <math.h>

#define HH  256      // d_model
#define NHD 32       // state halves
#define LL  8192     // sequence length
#define BB  16       // batch
#define HN  (HH*NHD) // 8192
#define BH  (BB*HH)  // 4096
#define LC  256      // chunk length
#define NG  (LL/LC)  // 32 chunks per row
#define NINST (BB*NG) // 512 chunk instances per h

typedef __attribute__((ext_vector_type(8))) short short8;
typedef __attribute__((ext_vector_type(4))) float floatx4;

__device__ __forceinline__ unsigned short f2bf(float f) {
  unsigned u = __float_as_uint(f);
  unsigned r = (u + 0x7FFF + ((u >> 16) & 1)) >> 16;
  return (unsigned short)r;
}
__device__ __forceinline__ unsigned packbf2(float a, float b) {
  return (unsigned)f2bf(a) | ((unsigned)f2bf(b) << 16);
}
__device__ __forceinline__ float gelu_t(float y) {
  float y2 = y * y;
  float arg = 1.5957691216f * fmaf(0.044715f * y2, y, y);
  return y / (1.f + __expf(-arg));
}

// ---------------------------------------------------------------------------
// Param precompute. P[k*HN + h*NHD + n]:
// 0=wr 1=wi 2=c0r 3=c0i 4=c1r 5=c1i 6=wLr 7=wLi 8=ar(dtA re) 9=ai(dtA im)
// ---------------------------------------------------------------------------
__global__ void precomp_kernel(const float* __restrict__ log_dt,
                               const float* __restrict__ A_real,
                               const float* __restrict__ A_imag,
                               const float* __restrict__ C_real,
                               const float* __restrict__ C_imag,
                               float* __restrict__ P) {
  int i = blockIdx.x * blockDim.x + threadIdx.x;
  if (i >= HN) return;
  int h = i >> 5;
  double dt  = exp((double)log_dt[h]);
  double Are = -exp((double)A_real[i]);
  double Aim = (double)A_imag[i];
  double ar = Are * dt, ai = Aim * dt;
  double ea = exp(ar);
  double wr = ea * cos(ai), wi = ea * sin(ai);
  double em_r = wr - 1.0, em_i = wi;
  double den = Are * Are + Aim * Aim;
  double rr = (em_r * Are + em_i * Aim) / den;
  double ri = (em_i * Are - em_r * Aim) / den;
  P[0*HN + i] = (float)wr;
  P[1*HN + i] = (float)wi;
  {
    double cr = (double)C_real[i], ci = (double)C_imag[i];
    P[2*HN + i] = (float)(2.0 * (cr * rr - ci * ri));
    P[3*HN + i] = (float)(2.0 * (cr * ri + ci * rr));
  }
  {
    double cr = (double)C_real[HN + i], ci = (double)C_imag[HN + i];
    P[4*HN + i] = (float)(2.0 * (cr * rr - ci * ri));
    P[5*HN + i] = (float)(2.0 * (cr * ri + ci * rr));
  }
  {
    double arL = ar * (double)LC, aiL = ai * (double)LC;
    double eaL = exp(arL);
    P[6*HN + i] = (float)(eaL * cos(aiL));
    P[7*HN + i] = (float)(eaL * sin(aiL));
  }
  P[8*HN + i] = (float)ar;
  P[9*HN + i] = (float)ai;
}

// W (512,256) row-major -> bf16
__global__ void wt_bf16_kernel(const float* __restrict__ W,
                               unsigned short* __restrict__ Wb) {
  int idx = blockIdx.x * 256 + threadIdx.x;
  Wb[idx] = f2bf(W[idx]);
}

// ---------------------------------------------------------------------------
// kf/kb tables: kf[h][d] = sum_n Re(c0_n w_n^d), kb same with c1. Direct exp.
// ---------------------------------------------------------------------------
__global__ __launch_bounds__(256) void kprep_kernel(const float* __restrict__ P,
                                                    float* __restrict__ Kf,
                                                    float* __restrict__ Kb) {
  int i = blockIdx.x * 256 + threadIdx.x;   // h*256 + d
  int d = i & 255, h = i >> 8;
  float fd = (float)d;
  float sf = 0.f, sb = 0.f;
  #pragma unroll 4
  for (int n = 0; n < NHD; ++n) {
    int j = h * NHD + n;
    float m  = __expf(fd * P[8*HN + j]);
    float ph = fd * P[9*HN + j];
    float cs = cosf(ph), sn = sinf(ph);
    float re = m * cs, im = m * sn;
    sf += P[2*HN + j] * re - P[3*HN + j] * im;
    sb += P[4*HN + j] * re - P[5*HN + j] * im;
  }
  Kf[i] = sf;
  Kb[i] = sb;
}

// ---------------------------------------------------------------------------
// T matrix per h: T[t][s] = kf[t-s] (s<t), kb[s-t-1] (s>t), kf[0]+D[h] (s==t)
// ---------------------------------------------------------------------------
__global__ __launch_bounds__(256) void tprep_kernel(const float* __restrict__ Kf,
                                                    const float* __restrict__ Kb,
                                                    const float* __restrict__ Dv,
                                                    unsigned short* __restrict__ T) {
  int h = blockIdx.x, q = blockIdx.y, s = threadIdx.x;
  const float* kf = Kf + h * 256;
  const float* kb = Kb + h * 256;
  float dh = Dv[h];
  unsigned short* tp = T + ((size_t)h * 256 + q * 64) * 256 + s;
  for (int tt = 0; tt < 64; ++tt) {
    int t = q * 64 + tt;
    int d = t - s;
    float v = (d > 0) ? kf[d] : ((d < 0) ? kb[-d - 1] : (kf[0] + dh));
    tp[(size_t)tt * 256] = f2bf(v);
  }
}

// ---------------------------------------------------------------------------
// V tables: rows 2n/2n+1 = Re/Im(w^{LC-1-s}) (fwd), rows 64+2n/+1 = Re/Im(w^s)
// ---------------------------------------------------------------------------
__global__ __launch_bounds__(256) void vprep_kernel(const float* __restrict__ P,
                                                    unsigned short* __restrict__ V) {
  int i = blockIdx.x * 256 + threadIdx.x;   // h*32 + n
  if (i >= HN) return;
  int n = i & 31, h = i >> 5;
  float wr = P[i], wi = P[HN + i];
  unsigned short* Vh = V + (size_t)h * 128 * 256;
  float er = 1.f, ei = 0.f;   // w^0
  for (int e = 0; e < LC; ++e) {
    Vh[(64 + 2*n) * 256 + e]       = f2bf(er);
    Vh[(64 + 2*n + 1) * 256 + e]   = f2bf(ei);
    Vh[(2*n) * 256 + (LC - 1 - e)] = f2bf(er);
    Vh[(2*n + 1) * 256 + (LC - 1 - e)] = f2bf(ei);
    float nr = er * wr - ei * wi;
    ei = er * wi + ei * wr;
    er = nr;
  }
}

// ---------------------------------------------------------------------------
// E-table (unchanged from R6, verified): E[h][t][k] bf16; k=2n: Re(c0 w^{t+1}),
// k=2n+1: -Im(c0 w^{t+1}); k=64+2n: Re(c1 w^{LC-1-t}), k=64+2n+1: -Im.
// ---------------------------------------------------------------------------
__global__ __launch_bounds__(256) void eprep_kernel(const float* __restrict__ P,
                                                    unsigned short* __restrict__ E) {
  int i = blockIdx.x * 256 + threadIdx.x;   // h*32 + n
  if (i >= HN) return;
  int n = i & 31, h = i >> 5;
  float wr = P[i], wi = P[HN + i];
  unsigned* ep = (unsigned*)E;
  {
    float cr = P[2*HN + i], ci = P[3*HN + i];
    float er = cr * wr - ci * wi;
    float ei = cr * wi + ci * wr;
    for (int t = 0; t < LC; ++t) {
      ep[((size_t)h * LC + t) * 64 + n] = packbf2(er, -ei);
      float nr = er * wr - ei * wi;
      float ni = er * wi + ei * wr;
      er = nr; ei = ni;
    }
  }
  {
    float er = P[4*HN + i], ei = P[5*HN + i];
    for (int t = LC - 1; t >= 0; --t) {
      ep[((size_t)h * LC + t) * 64 + 32 + n] = packbf2(er, -ei);
      float nr = er * wr - ei * wi;
      float ni = er * wi + ei * wr;
      er = nr; ei = ni;
    }
  }
}

// ---------------------------------------------------------------------------
// x (L, B*H) f32 -> Ub (B*H, L) bf16
// ---------------------------------------------------------------------------
__global__ void transpose_kernel(const float* __restrict__ x,
                                 unsigned short* __restrict__ Ub) {
  __shared__ float tile[32][33];
  int gx = blockIdx.x * 32;   // p
  int gy = blockIdx.y * 32;   // l
  int tx = threadIdx.x, ty = threadIdx.y;
  #pragma unroll
  for (int k2 = 0; k2 < 4; ++k2)
    tile[ty + 8*k2][tx] = x[(size_t)(gy + ty + 8*k2) * BH + gx + tx];
  __syncthreads();
  #pragma unroll
  for (int k2 = 0; k2 < 4; ++k2)
    Ub[(size_t)(gx + ty + 8*k2) * LL + gy + tx] = f2bf(tile[tx][ty + 8*k2]);
}

// ---------------------------------------------------------------------------
// Chunk-final states via MFMA: Sfin[h][inst][k] f32 (k: 0..63 fwd, 64..127 bwd)
// Block = (h, itile): 4 waves, wave w covers k-tiles {2w, 2w+1}.
// ---------------------------------------------------------------------------
__global__ __launch_bounds__(256) void sfin_mfma(const unsigned short* __restrict__ V,
                                                 const unsigned short* __restrict__ Ub,
                                                 float* __restrict__ Sfin) {
  int tid = threadIdx.x, w = tid >> 6, lane = tid & 63;
  int ln = lane & 15, lg = lane >> 4;
  int bid = blockIdx.x;
  int h = (bid & 7) * 32 + (bid >> 8);   // XCD-swizzled: one h-band per XCD
  int itile = (bid >> 3) & 31;
  int inst = itile * 16 + ln;
  int b = inst >> 5, g = inst & 31;
  const short8* U8 = (const short8*)Ub;
  const short8* V8 = (const short8*)V;
  size_t ub = (size_t)(b * 256 + h) * 1024 + g * 32 + lg;
  short8 Bf[8];
  #pragma unroll
  for (int ks = 0; ks < 8; ++ks) Bf[ks] = U8[ub + ks * 4];
  #pragma unroll
  for (int mi = 0; mi < 2; ++mi) {
    int mt = w * 2 + mi;
    floatx4 acc = (floatx4){0.f, 0.f, 0.f, 0.f};
    #pragma unroll
    for (int ks = 0; ks < 8; ++ks) {
      short8 Af = V8[((size_t)h * 128 + mt * 16 + ln) * 32 + ks * 4 + lg];
      acc = __builtin_amdgcn_mfma_f32_16x16x32_bf16(Af, Bf[ks], acc, 0, 0, 0);
    }
    // D: col=ln (inst), row=lg*4+r (k). Lane writes contiguous float4 along k.
    float* sp = Sfin + ((size_t)h * NINST + inst) * 128 + mt * 16 + lg * 4;
    *(float4*)sp = (float4){acc[0], acc[1], acc[2], acc[3]};
  }
}

// ---------------------------------------------------------------------------
// Cross-chunk scan: Sfin local finals -> incoming states, packed bf16 Sc.
// ---------------------------------------------------------------------------
__global__ __launch_bounds__(256) void scanB_kernel(const float* __restrict__ P,
                                                    const float* __restrict__ Sfin,
                                                    unsigned short* __restrict__ Sc) {
  int t = blockIdx.x * 256 + threadIdx.x;
  if (t >= BH * NHD) return;
  int n = t & 31, h = (t >> 5) & (HH - 1), b = t >> 13;
  float wlr = P[6*HN + h*NHD + n], wli = P[7*HN + h*NHD + n];
  unsigned* sc = (unsigned*)Sc;
  {
    float ar = 0.f, ai = 0.f;
    for (int g = 0; g < NG; ++g) {
      int inst = b * NG + g;
      sc[((size_t)h * NINST + inst) * 64 + n] = packbf2(ar, ai);
      const float* sp = Sfin + ((size_t)h * NINST + inst) * 128 + 2 * n;
      float lr = sp[0], li = sp[1];
      float nr = lr + wlr * ar - wli * ai;
      float ni = li + wlr * ai + wli * ar;
      ar = nr; ai = ni;
    }
  }
  {
    float ar = 0.f, ai = 0.f;
    for (int g = NG - 1; g >= 0; --g) {
      int inst = b * NG + g;
      sc[((size_t)h * NINST + inst) * 64 + 32 + n] = packbf2(ar, ai);
      const float* sp = Sfin + ((size_t)h * NINST + inst) * 128 + 64 + 2 * n;
      float lr = sp[0], li = sp[1];
      float nr = lr + wlr * ar - wli * ai;
      float ni = li + wlr * ai + wli * ar;
      ar = nr; ai = ni;
    }
  }
}

// ---------------------------------------------------------------------------
// Fused local Toeplitz conv + cross-chunk correction + gelu:
// y[t][inst] = gelu( T_h . u + E_h . Sc ), written bf16 to Y2 [b*H+h][l].
// Block = (h, itile); wave w iterates ttiles {w, w+4, w+8, w+12};
// B-fragments (u) and Sc-fragments register-resident across iterations.
// ---------------------------------------------------------------------------
__global__ __launch_bounds__(256) void yloc_corr(const unsigned short* __restrict__ T,
                                                 const unsigned short* __restrict__ E,
                                                 const unsigned short* __restrict__ Sc,
                                                 const unsigned short* __restrict__ Ub,
                                                 unsigned short* __restrict__ Y2) {
  int tid = threadIdx.x, w = tid >> 6, lane = tid & 63;
  int ln = lane & 15, lg = lane >> 4;
  int bid = blockIdx.x;
  int h = (bid & 7) * 32 + (bid >> 8);
  int itile = (bid >> 3) & 31;
  int inst = itile * 16 + ln;
  int b = inst >> 5, g = inst & 31;
  const short8* T8 = (const short8*)T;
  const short8* E8 = (const short8*)E;
  const short8* S8 = (const short8*)Sc;
  const short8* U8 = (const short8*)Ub;

  size_t ub = (size_t)(b * 256 + h) * 1024 + g * 32 + lg;
  short8 Bf[8];
  #pragma unroll
  for (int ks = 0; ks < 8; ++ks) Bf[ks] = U8[ub + ks * 4];
  size_t sr = ((size_t)h * NINST + inst) * 16 + lg;
  short8 Sf[4];
  #pragma unroll
  for (int ks = 0; ks < 4; ++ks) Sf[ks] = S8[sr + ks * 4];

  unsigned short* yrow = Y2 + (size_t)(b * 256 + h) * LL + g * 256;

  #pragma unroll
  for (int it = 0; it < 4; ++it) {
    int t0 = (w + 4 * it) * 16;
    floatx4 acc = (floatx4){0.f, 0.f, 0.f, 0.f};
    size_t tr = ((size_t)h * 256 + t0 + ln) * 32;
    #pragma unroll
    for (int ks = 0; ks < 8; ++ks) {
      short8 Af = T8[tr + ks * 4 + lg];
      acc = __builtin_amdgcn_mfma_f32_16x16x32_bf16(Af, Bf[ks], acc, 0, 0, 0);
    }
    size_t er = ((size_t)h * 256 + t0 + ln) * 16;
    #pragma unroll
    for (int ks = 0; ks < 4; ++ks) {
      short8 Af = E8[er + ks * 4 + lg];
      acc = __builtin_amdgcn_mfma_f32_16x16x32_bf16(Af, Sf[ks], acc, 0, 0, 0);
    }
    float y0 = gelu_t(acc[0]), y1 = gelu_t(acc[1]);
    float y2v = gelu_t(acc[2]), y3 = gelu_t(acc[3]);
    uint2 vv; vv.x = packbf2(y0, y1); vv.y = packbf2(y2v, y3);
    *(uint2*)(yrow + t0 + lg * 4) = vv;
  }
}

// ---------------------------------------------------------------------------
// Y2 (B*H, L) bf16 -> Yb (B*L, H) bf16 (k-contiguous rows for gemm B-frags)
// ---------------------------------------------------------------------------
__global__ void convT_kernel(const unsigned short* __restrict__ Y2,
                             unsigned short* __restrict__ Yb) {
  __shared__ unsigned short tile[32][33];
  int pb = blockIdx.x * 32;
  int lb = blockIdx.y * 32;
  int tx = threadIdx.x, ty = threadIdx.y;
  #pragma unroll
  for (int k2 = 0; k2 < 4; ++k2)
    tile[ty + 8*k2][tx] = Y2[(size_t)(pb + ty + 8*k2) * LL + lb + tx];
  __syncthreads();
  int b = pb >> 8, h0 = pb & 255;
  #pragma unroll
  for (int k2 = 0; k2 < 4; ++k2) {
    int r = ty + 8*k2;
    Yb[(size_t)(b * LL + lb + r) * HH + h0 + tx] = tile[tx][r];
  }
}

// ---------------------------------------------------------------------------
// MFMA GEMM + GLU: stage full 128x256 Y-tile to LDS once (XOR-swizzled),
// 16 waves: wave = (mgrp 0..7, ngrp 0..1): rows mgrp*32+{0,16,256,256+16},
// cols ngrp*64 + nf*16. One barrier total.
// ---------------------------------------------------------------------------
__global__ __launch_bounds__(1024, 4) void gemm_mfma(
    const unsigned short* __restrict__ Wb,
    const unsigned short* __restrict__ Yb,
    const float* __restrict__ bvec, float* __restrict__ out) {
  __shared__ __align__(16) unsigned short lds[32768];   // 64 KB
  int tid  = threadIdx.x;
  int w    = tid >> 6;
  int lane = tid & 63;
  int ln = lane & 15, lg = lane >> 4;
  int b  = blockIdx.x >> 6;
  int l0 = (blockIdx.x & 63) << 7;

  const short8* W8 = (const short8*)Wb;

  // stage: thread loads 4 x 16B chunks of its row, XOR-swizzled store
  {
    int r  = tid >> 3;              // 0..127 (row = l-col of tile)
    int c0 = (tid & 7) * 4;         // chunk base
    const short8* src = (const short8*)Yb + (size_t)(b * LL + l0 + r) * 32;
    short8* dst = (short8*)lds + r * 32;
    #pragma unroll
    for (int k = 0; k < 4; ++k) {
      int c = c0 + k;
      dst[c ^ (r & 7)] = src[c];
    }
  }
  __syncthreads();

  int mgrp = w >> 1, ngrp = w & 1;
  floatx4 acc[4][4];
  #pragma unroll
  for (int m = 0; m < 4; ++m)
    #pragma unroll
    for (int n = 0; n < 4; ++n) acc[m][n] = (floatx4){0.f, 0.f, 0.f, 0.f};

  const short8* L8 = (const short8*)lds;
  #pragma unroll
  for (int ks = 0; ks < 8; ++ks) {
    short8 Bf[4];
    #pragma unroll
    for (int nf = 0; nf < 4; ++nf) {
      int row = ngrp * 64 + nf * 16 + ln;
      Bf[nf] = L8[row * 32 + ((ks * 4 + lg) ^ (row & 7))];
    }
    #pragma unroll
    for (int mm = 0; mm < 4; ++mm) {
      int orow = mgrp * 32 + (mm & 1) * 16 + (mm >> 1) * 256 + ln;
      short8 Af = W8[(size_t)orow * 32 + ks * 4 + lg];
      #pragma unroll
      for (int nf = 0; nf < 4; ++nf)
        acc[mm][nf] = __builtin_amdgcn_mfma_f32_16x16x32_bf16(Af, Bf[nf], acc[mm][nf], 0, 0, 0);
    }
  }

  // epilogue: z1 rows = mgrp*32 + mm*16 (mm 0,1), z2 = same + 256 (acc[mm+2])
  #pragma unroll
  for (int mm = 0; mm < 2; ++mm) {
    int obase = mgrp * 32 + mm * 16 + lg * 4;
    #pragma unroll
    for (int r = 0; r < 4; ++r) {
      int o = obase + r;
      float b0 = bvec[o];
      float b1 = bvec[HH + o];
      float* op = out + ((size_t)(b * HH + o)) * LL + l0 + ngrp * 64 + ln;
      #pragma unroll
      for (int nf = 0; nf < 4; ++nf) {
        float z1 = acc[mm][nf][r] + b0;
        float z2 = acc[mm + 2][nf][r] + b1;
        op[nf * 16] = z1 / (1.f + __expf(-z2));
      }
    }
  }
}

// ---------------------------------------------------------------------------
extern "C" void kernel_launch(void* const* d_in, const int* in_sizes, int n_in,
                              void* d_out, int out_size, void* d_ws, size_t ws_size,
                              hipStream_t stream) {
  const float* x      = (const float*)d_in[0];
  const float* log_dt = (const float*)d_in[1];
  const float* A_real = (const float*)d_in[2];
  const float* A_imag = (const float*)d_in[3];
  const float* C_real = (const float*)d_in[4];
  const float* C_imag = (const float*)d_in[5];
  const float* Dv     = (const float*)d_in[6];
  const float* W      = (const float*)d_in[7];
  const float* bvec   = (const float*)d_in[8];
  float* out = (float*)d_out;

  char* ws = (char*)d_ws;
  float*          P  = (float*)ws;                          // 320 KB (10*HN*4)
  unsigned short* Wb = (unsigned short*)(ws + 524288);      // 256 KB
  float*          Kf = (float*)(ws + 786432);               // 256 KB
  float*          Kb = (float*)(ws + 1048576);              // 256 KB
  size_t OFF_UB = (size_t)2 << 20;                          // 2 MB
  size_t UB_BY  = (size_t)BH * LL * 2;                      // 64 MB
  size_t OFF_T  = OFF_UB + UB_BY;
  size_t T_BY   = (size_t)HH * 256 * 256 * 2;               // 33.5 MB
  size_t OFF_V  = OFF_T + T_BY;
  size_t V_BY   = (size_t)HH * 128 * 256 * 2;               // 16.8 MB
  size_t OFF_E  = OFF_V + V_BY;
  size_t E_BY   = (size_t)HH * LC * 128 * 2;                // 16.8 MB
  size_t OFF_SF = OFF_E + E_BY;
  size_t SF_BY  = (size_t)HH * NINST * 128 * 4;             // 67.1 MB
  size_t OFF_SC = OFF_SF + SF_BY;
  size_t SC_BY  = (size_t)HH * NINST * 128 * 2;             // 33.5 MB
  unsigned short* Ub   = (unsigned short*)(ws + OFF_UB);
  unsigned short* T    = (unsigned short*)(ws + OFF_T);
  unsigned short* V    = (unsigned short*)(ws + OFF_V);
  unsigned short* E    = (unsigned short*)(ws + OFF_E);
  float*          Sfin = (float*)(ws + OFF_SF);
  unsigned short* Sc   = (unsigned short*)(ws + OFF_SC);
  unsigned short* Y2   = (unsigned short*)(ws + OFF_SF);    // alias: Sfin dead after scanB
  unsigned short* Yb   = (unsigned short*)(ws + OFF_UB);    // alias: Ub dead after yloc

  precomp_kernel<<<HN / 256, 256, 0, stream>>>(log_dt, A_real, A_imag, C_real, C_imag, P);
  wt_bf16_kernel<<<512, 256, 0, stream>>>(W, Wb);
  kprep_kernel<<<HH * 256 / 256, 256, 0, stream>>>(P, Kf, Kb);
  eprep_kernel<<<HN / 256, 256, 0, stream>>>(P, E);
  vprep_kernel<<<HN / 256, 256, 0, stream>>>(P, V);
  tprep_kernel<<<dim3(HH, 4), 256, 0, stream>>>(Kf, Kb, Dv, T);
  transpose_kernel<<<dim3(BH / 32, LL / 32), dim3(32, 8), 0, stream>>>(x, Ub);
  sfin_mfma<<<HH * 32, 256, 0, stream>>>(V, Ub, Sfin);
  scanB_kernel<<<(BH * NHD) / 256, 256, 0, stream>>>(P, Sfin, Sc);
  yloc_corr<<<HH * 32, 256, 0, stream>>>(T, E, Sc, Ub, Y2);
  convT_kernel<<<dim3(BH / 32, LL / 32), dim3(32, 8), 0, stream>>>(Y2, Yb);
  gemm_mfma<<<BB * (LL / 128), 1024, 0, stream>>>(Wb, Yb, bvec, out);
}

// Round 10
// 541.804 us; speedup vs baseline: 1.7057x; 1.3038x over previous
//
#include <hip/hip_runtime.h>
#include <hip/hip_bf16.h>
#include <math.h>

#define HH  256      // d_model
#define NHD 32       // state halves
#define LL  8192     // sequence length
#define BB  16       // batch
#define HN  (HH*NHD) // 8192
#define BH  (BB*HH)  // 4096
#define LC  256      // chunk length
#define NG  (LL/LC)  // 32 chunks per row
#define NINST (BB*NG) // 512 chunk instances per h

typedef __attribute__((ext_vector_type(8))) short short8;
typedef __attribute__((ext_vector_type(4))) float floatx4;

__device__ __forceinline__ unsigned short f2bf(float f) {
  unsigned u = __float_as_uint(f);
  unsigned r = (u + 0x7FFF + ((u >> 16) & 1)) >> 16;
  return (unsigned short)r;
}
__device__ __forceinline__ unsigned packbf2(float a, float b) {
  return (unsigned)f2bf(a) | ((unsigned)f2bf(b) << 16);
}
__device__ __forceinline__ float gelu_t(float y) {
  float y2 = y * y;
  float arg = 1.5957691216f * fmaf(0.044715f * y2, y, y);
  return y / (1.f + __expf(-arg));
}

// ---------------------------------------------------------------------------
// Param precompute. P[k*HN + h*NHD + n]:
// 0=wr 1=wi 2=c0r 3=c0i 4=c1r 5=c1i 6=wLr 7=wLi 8=ar(dtA re) 9=ai(dtA im)
// ---------------------------------------------------------------------------
__global__ void precomp_kernel(const float* __restrict__ log_dt,
                               const float* __restrict__ A_real,
                               const float* __restrict__ A_imag,
                               const float* __restrict__ C_real,
                               const float* __restrict__ C_imag,
                               float* __restrict__ P) {
  int i = blockIdx.x * blockDim.x + threadIdx.x;
  if (i >= HN) return;
  int h = i >> 5;
  double dt  = exp((double)log_dt[h]);
  double Are = -exp((double)A_real[i]);
  double Aim = (double)A_imag[i];
  double ar = Are * dt, ai = Aim * dt;
  double ea = exp(ar);
  double wr = ea * cos(ai), wi = ea * sin(ai);
  double em_r = wr - 1.0, em_i = wi;
  double den = Are * Are + Aim * Aim;
  double rr = (em_r * Are + em_i * Aim) / den;
  double ri = (em_i * Are - em_r * Aim) / den;
  P[0*HN + i] = (float)wr;
  P[1*HN + i] = (float)wi;
  {
    double cr = (double)C_real[i], ci = (double)C_imag[i];
    P[2*HN + i] = (float)(2.0 * (cr * rr - ci * ri));
    P[3*HN + i] = (float)(2.0 * (cr * ri + ci * rr));
  }
  {
    double cr = (double)C_real[HN + i], ci = (double)C_imag[HN + i];
    P[4*HN + i] = (float)(2.0 * (cr * rr - ci * ri));
    P[5*HN + i] = (float)(2.0 * (cr * ri + ci * rr));
  }
  {
    double arL = ar * (double)LC, aiL = ai * (double)LC;
    double eaL = exp(arL);
    P[6*HN + i] = (float)(eaL * cos(aiL));
    P[7*HN + i] = (float)(eaL * sin(aiL));
  }
  P[8*HN + i] = (float)ar;
  P[9*HN + i] = (float)ai;
}

// W (512,256) row-major -> bf16
__global__ void wt_bf16_kernel(const float* __restrict__ W,
                               unsigned short* __restrict__ Wb) {
  int idx = blockIdx.x * 256 + threadIdx.x;
  Wb[idx] = f2bf(W[idx]);
}

// ---------------------------------------------------------------------------
// kf/kb tables: kf[h][d] = sum_n Re(c0_n w_n^d), kb same with c1.
// ---------------------------------------------------------------------------
__global__ __launch_bounds__(256) void kprep_kernel(const float* __restrict__ P,
                                                    float* __restrict__ Kf,
                                                    float* __restrict__ Kb) {
  int i = blockIdx.x * 256 + threadIdx.x;   // h*256 + d
  int d = i & 255, h = i >> 8;
  float fd = (float)d;
  float sf = 0.f, sb = 0.f;
  #pragma unroll 4
  for (int n = 0; n < NHD; ++n) {
    int j = h * NHD + n;
    float m  = __expf(fd * P[8*HN + j]);
    float ph = fd * P[9*HN + j];
    float cs = cosf(ph), sn = sinf(ph);
    float re = m * cs, im = m * sn;
    sf += P[2*HN + j] * re - P[3*HN + j] * im;
    sb += P[4*HN + j] * re - P[5*HN + j] * im;
  }
  Kf[i] = sf;
  Kb[i] = sb;
}

// ---------------------------------------------------------------------------
// T' fragment-order: chunk idx (((h*16+tt)*8+ks)*16+ln)*4+lg holds
// T[t=tt*16+ln][s=ks*32+lg*8+e], e in [0,8).
// ---------------------------------------------------------------------------
__global__ __launch_bounds__(256) void tprep_kernel(const float* __restrict__ Kf,
                                                    const float* __restrict__ Kb,
                                                    const float* __restrict__ Dv,
                                                    unsigned short* __restrict__ T) {
  int h = blockIdx.x, tt = blockIdx.y;
  const float* kf = Kf + h * 256;
  const float* kb = Kb + h * 256;
  float dh = Dv[h];
  short8* out = (short8*)T;
  #pragma unroll
  for (int i = 0; i < 2; ++i) {
    int j = i * 256 + threadIdx.x;          // 0..511 = ks*64 + ln*4 + lg
    int ks = j >> 6, ln = (j >> 2) & 15, lg = j & 3;
    int t = tt * 16 + ln;
    short8 vv;
    #pragma unroll
    for (int e = 0; e < 8; ++e) {
      int s = ks * 32 + lg * 8 + e;
      int d = t - s;
      float v = (d > 0) ? kf[d] : ((d < 0) ? kb[-d - 1] : (kf[0] + dh));
      vv[e] = (short)f2bf(v);
    }
    out[(size_t)(h * 16 + tt) * 512 + j] = vv;
  }
}

// ---------------------------------------------------------------------------
// E' fragment-order: chunk (((h*16+tt)*4+ks)*16+ln)*4+lg holds E[t][k],
// t=tt*16+ln, k=ks*32+lg*8+e. k<64: pairs (Re, -Im) of c0*w^{t+1};
// k>=64: pairs of c1*w^{LC-1-t}. Direct exp.
// ---------------------------------------------------------------------------
__global__ __launch_bounds__(256) void eprep_kernel(const float* __restrict__ P,
                                                    unsigned short* __restrict__ E) {
  int h = blockIdx.x, tt = blockIdx.y;
  int j = threadIdx.x;                       // 0..255 = ks*64 + ln*4 + lg
  int ks = j >> 6, ln = (j >> 2) & 15, lg = j & 3;
  int t = tt * 16 + ln;
  int k0 = ks * 32 + lg * 8;
  short8 vv;
  if (k0 < 64) {
    float d = (float)(t + 1);
    #pragma unroll
    for (int q = 0; q < 4; ++q) {
      int n = (k0 >> 1) + q;
      int idx = h * NHD + n;
      float m  = __expf(d * P[8*HN + idx]);
      float ph = d * P[9*HN + idx];
      float re = m * cosf(ph), im = m * sinf(ph);
      float cr = P[2*HN + idx], ci = P[3*HN + idx];
      float zr = cr * re - ci * im;
      float zi = cr * im + ci * re;
      vv[2*q]   = (short)f2bf(zr);
      vv[2*q+1] = (short)f2bf(-zi);
    }
  } else {
    float d = (float)(LC - 1 - t);
    #pragma unroll
    for (int q = 0; q < 4; ++q) {
      int n = ((k0 - 64) >> 1) + q;
      int idx = h * NHD + n;
      float m  = __expf(d * P[8*HN + idx]);
      float ph = d * P[9*HN + idx];
      float re = m * cosf(ph), im = m * sinf(ph);
      float cr = P[4*HN + idx], ci = P[5*HN + idx];
      float zr = cr * re - ci * im;
      float zi = cr * im + ci * re;
      vv[2*q]   = (short)f2bf(zr);
      vv[2*q+1] = (short)f2bf(-zi);
    }
  }
  ((short8*)E)[(size_t)(h * 16 + tt) * 256 + j] = vv;
}

// ---------------------------------------------------------------------------
// V' fragment-order: chunk (((h*8+mt)*8+ks)*16+ln)*4+lg, row=mt*16+ln:
// row<64: comp(row&1) of w^{LC-1-s}; row>=64: comp of w^s; s=ks*32+lg*8+e.
// ---------------------------------------------------------------------------
__global__ __launch_bounds__(256) void vprep_kernel(const float* __restrict__ P,
                                                    unsigned short* __restrict__ V) {
  int h = blockIdx.x, mt = blockIdx.y;       // mt in [0,8)
  #pragma unroll
  for (int i = 0; i < 2; ++i) {
    int j = i * 256 + threadIdx.x;           // 0..511
    int ks = j >> 6, ln = (j >> 2) & 15, lg = j & 3;
    int row = mt * 16 + ln;
    int dir = row >> 6, nc = row & 63;
    int n = nc >> 1, comp = nc & 1;
    int idx = h * NHD + n;
    float arn = P[8*HN + idx], ain = P[9*HN + idx];
    short8 vv;
    #pragma unroll
    for (int e = 0; e < 8; ++e) {
      int s = ks * 32 + lg * 8 + e;
      float d = (float)(dir ? s : (LC - 1 - s));
      float m = __expf(d * arn);
      float ph = d * ain;
      float v = m * (comp ? sinf(ph) : cosf(ph));
      vv[e] = (short)f2bf(v);
    }
    ((short8*)V)[(size_t)(h * 8 + mt) * 512 + j] = vv;
  }
}

// ---------------------------------------------------------------------------
// x (L,B,H) f32 -> UF fragment-order bf16: chunk (((h*32+it)*8+ks)*16+ln)*4+lg
// = u[b][h][l = g*256 + ks*32 + lg*8 + e], inst = b*32+g = it*16+ln.
// ---------------------------------------------------------------------------
__global__ __launch_bounds__(256) void transpose_kernel(const float* __restrict__ x,
                                                        unsigned short* __restrict__ UF) {
  __shared__ unsigned short tile[32][264];
  int b  = blockIdx.x;
  int lb = blockIdx.y * 32;
  int tid = threadIdx.x;
  int g = lb >> 8, ks = (lb & 255) >> 5;
  int inst = b * 32 + g, it = inst >> 4, lnw = inst & 15;
  #pragma unroll
  for (int i = 0; i < 8; ++i) {
    int idx = i * 256 + tid;                 // 0..2047
    int row = idx >> 6, c4 = idx & 63;
    float4 v = *(const float4*)(x + (size_t)(lb + row) * BH + b * 256 + c4 * 4);
    ushort4 u4v;
    u4v.x = f2bf(v.x); u4v.y = f2bf(v.y); u4v.z = f2bf(v.z); u4v.w = f2bf(v.w);
    *(ushort4*)&tile[row][c4 * 4] = u4v;
  }
  __syncthreads();
  short8* out = (short8*)UF;
  #pragma unroll
  for (int i = 0; i < 4; ++i) {
    int j = i * 256 + tid;                   // 0..1023
    int h = j >> 2, lg = j & 3;
    short8 vv;
    #pragma unroll
    for (int e = 0; e < 8; ++e) vv[e] = (short)tile[lg * 8 + e][h];
    out[(size_t)(h * 32 + it) * 512 + ks * 64 + lnw * 4 + lg] = vv;
  }
}

// ---------------------------------------------------------------------------
// Chunk-final states: Sfin[h][inst][k] f32 = V'_h . u.
// 256 threads / 4 waves; wave w covers mt = w*2 + mi. bid = itile*256 + h
// (bid%8 = h%8 -> all 32 blocks of an h on one XCD; V'_h L2-resident).
// ---------------------------------------------------------------------------
__global__ __launch_bounds__(256) void sfin_mfma(const unsigned short* __restrict__ V,
                                                 const unsigned short* __restrict__ UF,
                                                 float* __restrict__ Sfin) {
  int tid = threadIdx.x, w = tid >> 6, lane = tid & 63;
  int ln = lane & 15, lg = lane >> 4;
  int bid = blockIdx.x;
  int h = bid & 255, itile = bid >> 8;
  const short8* U8 = (const short8*)UF;
  const short8* V8 = (const short8*)V;
  size_t ub = (size_t)(h * 32 + itile) * 512 + ln * 4 + lg;
  short8 Bf[8];
  #pragma unroll
  for (int ks = 0; ks < 8; ++ks) Bf[ks] = U8[ub + ks * 64];
  int inst = itile * 16 + ln;
  #pragma unroll
  for (int mi = 0; mi < 2; ++mi) {
    int mt = w * 2 + mi;
    floatx4 acc = (floatx4){0.f, 0.f, 0.f, 0.f};
    size_t vb = (size_t)(h * 8 + mt) * 512 + ln * 4 + lg;
    #pragma unroll
    for (int ks = 0; ks < 8; ++ks) {
      short8 Af = V8[vb + ks * 64];
      acc = __builtin_amdgcn_mfma_f32_16x16x32_bf16(Af, Bf[ks], acc, 0, 0, 0);
    }
    float* sp = Sfin + ((size_t)h * NINST + inst) * 128 + mt * 16 + lg * 4;
    *(float4*)sp = (float4){acc[0], acc[1], acc[2], acc[3]};
  }
}

// ---------------------------------------------------------------------------
// Cross-chunk scan: Sfin -> incoming states, written in Sc' fragment order:
// chunk (((h*32+it)*4+ks)*16+ln)*4+lg, k = ks*32+lg*8+e.
// ---------------------------------------------------------------------------
__global__ __launch_bounds__(256) void scanB_kernel(const float* __restrict__ P,
                                                    const float* __restrict__ Sfin,
                                                    unsigned short* __restrict__ Sc) {
  int t = blockIdx.x * 256 + threadIdx.x;
  if (t >= BH * NHD) return;
  int n = t & 31, h = (t >> 5) & 255, b = t >> 13;
  float wlr = P[6*HN + h*NHD + n], wli = P[7*HN + h*NHD + n];
  unsigned* sc = (unsigned*)Sc;
  {
    int k = 2 * n;
    int ks = k >> 5, lg = (k & 31) >> 3, eh = (k & 7) >> 1;
    float ar = 0.f, ai = 0.f;
    for (int g = 0; g < NG; ++g) {
      int inst = b * NG + g;
      int it = inst >> 4, ln = inst & 15;
      size_t chunk = (size_t)(h * 32 + it) * 256 + ks * 64 + ln * 4 + lg;
      sc[chunk * 4 + eh] = packbf2(ar, ai);
      const float* sp = Sfin + ((size_t)h * NINST + inst) * 128 + 2 * n;
      float lr = sp[0], li = sp[1];
      float nr = lr + wlr * ar - wli * ai;
      float ni = li + wlr * ai + wli * ar;
      ar = nr; ai = ni;
    }
  }
  {
    int k = 64 + 2 * n;
    int ks = k >> 5, lg = (k & 31) >> 3, eh = (k & 7) >> 1;
    float ar = 0.f, ai = 0.f;
    for (int g = NG - 1; g >= 0; --g) {
      int inst = b * NG + g;
      int it = inst >> 4, ln = inst & 15;
      size_t chunk = (size_t)(h * 32 + it) * 256 + ks * 64 + ln * 4 + lg;
      sc[chunk * 4 + eh] = packbf2(ar, ai);
      const float* sp = Sfin + ((size_t)h * NINST + inst) * 128 + 64 + 2 * n;
      float lr = sp[0], li = sp[1];
      float nr = lr + wlr * ar - wli * ai;
      float ni = li + wlr * ai + wli * ar;
      ar = nr; ai = ni;
    }
  }
}

// ---------------------------------------------------------------------------
// Fused local Toeplitz conv + correction + gelu: y = gelu(T'_h.u + E'_h.Sc).
// 256 threads / 4 waves; wave w does tt = w*4 + it4. B (Bf+Sf) register-
// resident across all 4 t-tiles. bid = itile*256 + h.
// ---------------------------------------------------------------------------
__global__ __launch_bounds__(256) void yloc_corr(const unsigned short* __restrict__ T,
                                                 const unsigned short* __restrict__ E,
                                                 const unsigned short* __restrict__ Sc,
                                                 const unsigned short* __restrict__ UF,
                                                 unsigned short* __restrict__ Y2) {
  int tid = threadIdx.x, w = tid >> 6, lane = tid & 63;
  int ln = lane & 15, lg = lane >> 4;
  int bid = blockIdx.x;
  int h = bid & 255, itile = bid >> 8;
  int inst = itile * 16 + ln;
  int b = inst >> 5, g = inst & 31;
  const short8* T8 = (const short8*)T;
  const short8* E8 = (const short8*)E;
  const short8* S8 = (const short8*)Sc;
  const short8* U8 = (const short8*)UF;

  size_t ub = (size_t)(h * 32 + itile) * 512 + ln * 4 + lg;
  short8 Bf[8];
  #pragma unroll
  for (int ks = 0; ks < 8; ++ks) Bf[ks] = U8[ub + ks * 64];
  size_t sb = (size_t)(h * 32 + itile) * 256 + ln * 4 + lg;
  short8 Sf[4];
  #pragma unroll
  for (int ks = 0; ks < 4; ++ks) Sf[ks] = S8[sb + ks * 64];

  unsigned short* yrow = Y2 + (size_t)(b * 256 + h) * LL + g * 256;

  #pragma unroll
  for (int it4 = 0; it4 < 4; ++it4) {
    int tt = w * 4 + it4;
    floatx4 acc = (floatx4){0.f, 0.f, 0.f, 0.f};
    size_t tb = (size_t)(h * 16 + tt) * 512 + ln * 4 + lg;
    #pragma unroll
    for (int ks = 0; ks < 8; ++ks) {
      short8 Af = T8[tb + ks * 64];
      acc = __builtin_amdgcn_mfma_f32_16x16x32_bf16(Af, Bf[ks], acc, 0, 0, 0);
    }
    size_t eb = (size_t)(h * 16 + tt) * 256 + ln * 4 + lg;
    #pragma unroll
    for (int ks = 0; ks < 4; ++ks) {
      short8 Af = E8[eb + ks * 64];
      acc = __builtin_amdgcn_mfma_f32_16x16x32_bf16(Af, Sf[ks], acc, 0, 0, 0);
    }
    float y0 = gelu_t(acc[0]), y1 = gelu_t(acc[1]);
    float y2v = gelu_t(acc[2]), y3 = gelu_t(acc[3]);
    uint2 vv; vv.x = packbf2(y0, y1); vv.y = packbf2(y2v, y3);
    *(uint2*)(yrow + tt * 16 + lg * 4) = vv;
  }
}

// ---------------------------------------------------------------------------
// Y2 (B*H, L) bf16 -> Yb (B*L, H) bf16
// ---------------------------------------------------------------------------
__global__ void convT_kernel(const unsigned short* __restrict__ Y2,
                             unsigned short* __restrict__ Yb) {
  __shared__ unsigned short tile[32][33];
  int pb = blockIdx.x * 32;
  int lb = blockIdx.y * 32;
  int tx = threadIdx.x, ty = threadIdx.y;
  #pragma unroll
  for (int k2 = 0; k2 < 4; ++k2)
    tile[ty + 8*k2][tx] = Y2[(size_t)(pb + ty + 8*k2) * LL + lb + tx];
  __syncthreads();
  int b = pb >> 8, h0 = pb & 255;
  #pragma unroll
  for (int k2 = 0; k2 < 4; ++k2) {
    int r = ty + 8*k2;
    Yb[(size_t)(b * LL + lb + r) * HH + h0 + tx] = tile[tx][r];
  }
}

// ---------------------------------------------------------------------------
// MFMA GEMM + GLU (LDS-staged XOR-swizzled, proven since R7)
// ---------------------------------------------------------------------------
__global__ __launch_bounds__(1024, 4) void gemm_mfma(
    const unsigned short* __restrict__ Wb,
    const unsigned short* __restrict__ Yb,
    const float* __restrict__ bvec, float* __restrict__ out) {
  __shared__ __align__(16) unsigned short lds[32768];   // 64 KB
  int tid  = threadIdx.x;
  int w    = tid >> 6;
  int lane = tid & 63;
  int ln = lane & 15, lg = lane >> 4;
  int b  = blockIdx.x >> 6;
  int l0 = (blockIdx.x & 63) << 7;

  const short8* W8 = (const short8*)Wb;

  {
    int r  = tid >> 3;
    int c0 = (tid & 7) * 4;
    const short8* src = (const short8*)Yb + (size_t)(b * LL + l0 + r) * 32;
    short8* dst = (short8*)lds + r * 32;
    #pragma unroll
    for (int k = 0; k < 4; ++k) {
      int c = c0 + k;
      dst[c ^ (r & 7)] = src[c];
    }
  }
  __syncthreads();

  int mgrp = w >> 1, ngrp = w & 1;
  floatx4 acc[4][4];
  #pragma unroll
  for (int m = 0; m < 4; ++m)
    #pragma unroll
    for (int n = 0; n < 4; ++n) acc[m][n] = (floatx4){0.f, 0.f, 0.f, 0.f};

  const short8* L8 = (const short8*)lds;
  #pragma unroll
  for (int ks = 0; ks < 8; ++ks) {
    short8 Bf[4];
    #pragma unroll
    for (int nf = 0; nf < 4; ++nf) {
      int row = ngrp * 64 + nf * 16 + ln;
      Bf[nf] = L8[row * 32 + ((ks * 4 + lg) ^ (row & 7))];
    }
    #pragma unroll
    for (int mm = 0; mm < 4; ++mm) {
      int orow = mgrp * 32 + (mm & 1) * 16 + (mm >> 1) * 256 + ln;
      short8 Af = W8[(size_t)orow * 32 + ks * 4 + lg];
      #pragma unroll
      for (int nf = 0; nf < 4; ++nf)
        acc[mm][nf] = __builtin_amdgcn_mfma_f32_16x16x32_bf16(Af, Bf[nf], acc[mm][nf], 0, 0, 0);
    }
  }

  #pragma unroll
  for (int mm = 0; mm < 2; ++mm) {
    int obase = mgrp * 32 + mm * 16 + lg * 4;
    #pragma unroll
    for (int r = 0; r < 4; ++r) {
      int o = obase + r;
      float b0 = bvec[o];
      float b1 = bvec[HH + o];
      float* op = out + ((size_t)(b * HH + o)) * LL + l0 + ngrp * 64 + ln;
      #pragma unroll
      for (int nf = 0; nf < 4; ++nf) {
        float z1 = acc[mm][nf][r] + b0;
        float z2 = acc[mm + 2][nf][r] + b1;
        op[nf * 16] = z1 / (1.f + __expf(-z2));
      }
    }
  }
}

// ---------------------------------------------------------------------------
extern "C" void kernel_launch(void* const* d_in, const int* in_sizes, int n_in,
                              void* d_out, int out_size, void* d_ws, size_t ws_size,
                              hipStream_t stream) {
  const float* x      = (const float*)d_in[0];
  const float* log_dt = (const float*)d_in[1];
  const float* A_real = (const float*)d_in[2];
  const float* A_imag = (const float*)d_in[3];
  const float* C_real = (const float*)d_in[4];
  const float* C_imag = (const float*)d_in[5];
  const float* Dv     = (const float*)d_in[6];
  const float* W      = (const float*)d_in[7];
  const float* bvec   = (const float*)d_in[8];
  float* out = (float*)d_out;

  // d_out doubles as scratch (serial: write -> read -> full overwrite by gemm):
  //   Y2   = d_out[0 : 64MiB)   bf16 (B*H, L), written by yloc, read by convT
  //   Sfin = d_out[64 : 128MiB) f32, written by sfin, read by scanB
  unsigned short* Y2   = (unsigned short*)d_out;
  float*          Sfin = (float*)d_out + 16777216;

  // ws: all regions dedicated (no aliasing). Total 226 MiB.
  char* ws = (char*)d_ws;
  float*          P  = (float*)ws;                          // 320 KB
  unsigned short* Wb = (unsigned short*)(ws + 524288);      // 256 KB
  float*          Kf = (float*)(ws + 786432);               // 256 KB
  float*          Kb = (float*)(ws + 1048576);              // 256 KB
  size_t OFF_UF = (size_t)2 << 20;                          // [2, 66) MiB
  size_t OFF_T  = OFF_UF + ((size_t)256 * 32 * 512 * 16);   // [66, 98) MiB
  size_t OFF_E  = OFF_T + ((size_t)256 * 16 * 512 * 16);    // [98, 114) MiB
  size_t OFF_V  = OFF_E + ((size_t)256 * 16 * 256 * 16);    // [114, 130) MiB
  size_t OFF_SC = OFF_V + ((size_t)256 * 8 * 512 * 16);     // [130, 162) MiB
  size_t OFF_YB = OFF_SC + ((size_t)256 * 32 * 256 * 16);   // [162, 226) MiB
  unsigned short* UF = (unsigned short*)(ws + OFF_UF);
  unsigned short* T  = (unsigned short*)(ws + OFF_T);
  unsigned short* E  = (unsigned short*)(ws + OFF_E);
  unsigned short* V  = (unsigned short*)(ws + OFF_V);
  unsigned short* Sc = (unsigned short*)(ws + OFF_SC);
  unsigned short* Yb = (unsigned short*)(ws + OFF_YB);

  precomp_kernel<<<HN / 256, 256, 0, stream>>>(log_dt, A_real, A_imag, C_real, C_imag, P);
  wt_bf16_kernel<<<512, 256, 0, stream>>>(W, Wb);
  kprep_kernel<<<HH * 256 / 256, 256, 0, stream>>>(P, Kf, Kb);
  tprep_kernel<<<dim3(HH, 16), 256, 0, stream>>>(Kf, Kb, Dv, T);
  eprep_kernel<<<dim3(HH, 16), 256, 0, stream>>>(P, E);
  vprep_kernel<<<dim3(HH, 8), 256, 0, stream>>>(P, V);
  transpose_kernel<<<dim3(BB, LL / 32), 256, 0, stream>>>(x, UF);
  sfin_mfma<<<32 * 256, 256, 0, stream>>>(V, UF, Sfin);
  scanB_kernel<<<(BH * NHD) / 256, 256, 0, stream>>>(P, Sfin, Sc);
  yloc_corr<<<32 * 256, 256, 0, stream>>>(T, E, Sc, UF, Y2);
  convT_kernel<<<dim3(BH / 32, LL / 32), dim3(32, 8), 0, stream>>>(Y2, Yb);
  gemm_mfma<<<BB * (LL / 128), 1024, 0, stream>>>(Wb, Yb, bvec, out);
}

// Round 11
// 361.897 us; speedup vs baseline: 2.5537x; 1.4971x over previous
//
#include <hip/hip_runtime.h>
#include <hip/hip_bf16.h>
#include <math.h>

#define HH  256      // d_model
#define NHD 32       // state halves
#define LL  8192     // sequence length
#define BB  16       // batch
#define HN  (HH*NHD) // 8192
#define BH  (BB*HH)  // 4096
#define LC  256      // chunk length
#define NG  (LL/LC)  // 32 chunks per row
#define NINST (BB*NG) // 512 chunk instances per h

typedef __attribute__((ext_vector_type(8))) short short8;
typedef __attribute__((ext_vector_type(4))) float floatx4;

__device__ __forceinline__ unsigned short f2bf(float f) {
  unsigned u = __float_as_uint(f);
  unsigned r = (u + 0x7FFF + ((u >> 16) & 1)) >> 16;
  return (unsigned short)r;
}
__device__ __forceinline__ unsigned packbf2(float a, float b) {
  return (unsigned)f2bf(a) | ((unsigned)f2bf(b) << 16);
}
__device__ __forceinline__ float gelu_t(float y) {
  float y2 = y * y;
  float arg = 1.5957691216f * fmaf(0.044715f * y2, y, y);
  return y / (1.f + __expf(-arg));
}

// ---------------------------------------------------------------------------
// Param precompute. P[k*HN + h*NHD + n]:
// 0=wr 1=wi 2=c0r 3=c0i 4=c1r 5=c1i 6=wLr 7=wLi 8=ar(dtA re) 9=ai(dtA im)
// ---------------------------------------------------------------------------
__global__ void precomp_kernel(const float* __restrict__ log_dt,
                               const float* __restrict__ A_real,
                               const float* __restrict__ A_imag,
                               const float* __restrict__ C_real,
                               const float* __restrict__ C_imag,
                               float* __restrict__ P) {
  int i = blockIdx.x * blockDim.x + threadIdx.x;
  if (i >= HN) return;
  int h = i >> 5;
  double dt  = exp((double)log_dt[h]);
  double Are = -exp((double)A_real[i]);
  double Aim = (double)A_imag[i];
  double ar = Are * dt, ai = Aim * dt;
  double ea = exp(ar);
  double wr = ea * cos(ai), wi = ea * sin(ai);
  double em_r = wr - 1.0, em_i = wi;
  double den = Are * Are + Aim * Aim;
  double rr = (em_r * Are + em_i * Aim) / den;
  double ri = (em_i * Are - em_r * Aim) / den;
  P[0*HN + i] = (float)wr;
  P[1*HN + i] = (float)wi;
  {
    double cr = (double)C_real[i], ci = (double)C_imag[i];
    P[2*HN + i] = (float)(2.0 * (cr * rr - ci * ri));
    P[3*HN + i] = (float)(2.0 * (cr * ri + ci * rr));
  }
  {
    double cr = (double)C_real[HN + i], ci = (double)C_imag[HN + i];
    P[4*HN + i] = (float)(2.0 * (cr * rr - ci * ri));
    P[5*HN + i] = (float)(2.0 * (cr * ri + ci * rr));
  }
  {
    double arL = ar * (double)LC, aiL = ai * (double)LC;
    double eaL = exp(arL);
    P[6*HN + i] = (float)(eaL * cos(aiL));
    P[7*HN + i] = (float)(eaL * sin(aiL));
  }
  P[8*HN + i] = (float)ar;
  P[9*HN + i] = (float)ai;
}

// ---------------------------------------------------------------------------
// W (512,256) f32 -> Wf fragment-order bf16:
// chunk ((og*8+ks)*16+ln)*4+lg holds W[og*16+ln][ks*32+lg*8+e], e in [0,8).
// ---------------------------------------------------------------------------
__global__ __launch_bounds__(256) void wt_frag_kernel(const float* __restrict__ W,
                                                      unsigned short* __restrict__ Wf) {
  int og = blockIdx.x;                       // 0..31
  #pragma unroll
  for (int i = 0; i < 2; ++i) {
    int j = i * 256 + threadIdx.x;           // 0..511 = ks*64 + ln*4 + lg
    int ks = j >> 6, ln = (j >> 2) & 15, lg = j & 3;
    const float* src = W + (size_t)(og * 16 + ln) * 256 + ks * 32 + lg * 8;
    short8 vv;
    #pragma unroll
    for (int e = 0; e < 8; ++e) vv[e] = (short)f2bf(src[e]);
    ((short8*)Wf)[og * 512 + j] = vv;
  }
}

// ---------------------------------------------------------------------------
// kf/kb tables: kf[h][d] = sum_n Re(c0_n w_n^d), kb same with c1.
// ---------------------------------------------------------------------------
__global__ __launch_bounds__(256) void kprep_kernel(const float* __restrict__ P,
                                                    float* __restrict__ Kf,
                                                    float* __restrict__ Kb) {
  int i = blockIdx.x * 256 + threadIdx.x;   // h*256 + d
  int d = i & 255, h = i >> 8;
  float fd = (float)d;
  float sf = 0.f, sb = 0.f;
  #pragma unroll 4
  for (int n = 0; n < NHD; ++n) {
    int j = h * NHD + n;
    float m  = __expf(fd * P[8*HN + j]);
    float ph = fd * P[9*HN + j];
    float cs = cosf(ph), sn = sinf(ph);
    float re = m * cs, im = m * sn;
    sf += P[2*HN + j] * re - P[3*HN + j] * im;
    sb += P[4*HN + j] * re - P[5*HN + j] * im;
  }
  Kf[i] = sf;
  Kb[i] = sb;
}

// ---------------------------------------------------------------------------
// T' fragment-order: chunk idx (((h*16+tt)*8+ks)*16+ln)*4+lg holds
// T[t=tt*16+ln][s=ks*32+lg*8+e], e in [0,8).
// ---------------------------------------------------------------------------
__global__ __launch_bounds__(256) void tprep_kernel(const float* __restrict__ Kf,
                                                    const float* __restrict__ Kb,
                                                    const float* __restrict__ Dv,
                                                    unsigned short* __restrict__ T) {
  int h = blockIdx.x, tt = blockIdx.y;
  const float* kf = Kf + h * 256;
  const float* kb = Kb + h * 256;
  float dh = Dv[h];
  short8* out = (short8*)T;
  #pragma unroll
  for (int i = 0; i < 2; ++i) {
    int j = i * 256 + threadIdx.x;          // 0..511 = ks*64 + ln*4 + lg
    int ks = j >> 6, ln = (j >> 2) & 15, lg = j & 3;
    int t = tt * 16 + ln;
    short8 vv;
    #pragma unroll
    for (int e = 0; e < 8; ++e) {
      int s = ks * 32 + lg * 8 + e;
      int d = t - s;
      float v = (d > 0) ? kf[d] : ((d < 0) ? kb[-d - 1] : (kf[0] + dh));
      vv[e] = (short)f2bf(v);
    }
    out[(size_t)(h * 16 + tt) * 512 + j] = vv;
  }
}

// ---------------------------------------------------------------------------
// E' fragment-order: chunk (((h*16+tt)*4+ks)*16+ln)*4+lg holds E[t][k],
// t=tt*16+ln, k=ks*32+lg*8+e. k<64: pairs (Re, -Im) of c0*w^{t+1};
// k>=64: pairs of c1*w^{LC-1-t}. Direct exp.
// ---------------------------------------------------------------------------
__global__ __launch_bounds__(256) void eprep_kernel(const float* __restrict__ P,
                                                    unsigned short* __restrict__ E) {
  int h = blockIdx.x, tt = blockIdx.y;
  int j = threadIdx.x;                       // 0..255 = ks*64 + ln*4 + lg
  int ks = j >> 6, ln = (j >> 2) & 15, lg = j & 3;
  int t = tt * 16 + ln;
  int k0 = ks * 32 + lg * 8;
  short8 vv;
  if (k0 < 64) {
    float d = (float)(t + 1);
    #pragma unroll
    for (int q = 0; q < 4; ++q) {
      int n = (k0 >> 1) + q;
      int idx = h * NHD + n;
      float m  = __expf(d * P[8*HN + idx]);
      float ph = d * P[9*HN + idx];
      float re = m * cosf(ph), im = m * sinf(ph);
      float cr = P[2*HN + idx], ci = P[3*HN + idx];
      float zr = cr * re - ci * im;
      float zi = cr * im + ci * re;
      vv[2*q]   = (short)f2bf(zr);
      vv[2*q+1] = (short)f2bf(-zi);
    }
  } else {
    float d = (float)(LC - 1 - t);
    #pragma unroll
    for (int q = 0; q < 4; ++q) {
      int n = ((k0 - 64) >> 1) + q;
      int idx = h * NHD + n;
      float m  = __expf(d * P[8*HN + idx]);
      float ph = d * P[9*HN + idx];
      float re = m * cosf(ph), im = m * sinf(ph);
      float cr = P[4*HN + idx], ci = P[5*HN + idx];
      float zr = cr * re - ci * im;
      float zi = cr * im + ci * re;
      vv[2*q]   = (short)f2bf(zr);
      vv[2*q+1] = (short)f2bf(-zi);
    }
  }
  ((short8*)E)[(size_t)(h * 16 + tt) * 256 + j] = vv;
}

// ---------------------------------------------------------------------------
// V' fragment-order: chunk (((h*8+mt)*8+ks)*16+ln)*4+lg, row=mt*16+ln:
// row<64: comp(row&1) of w^{LC-1-s}; row>=64: comp of w^s; s=ks*32+lg*8+e.
// ---------------------------------------------------------------------------
__global__ __launch_bounds__(256) void vprep_kernel(const float* __restrict__ P,
                                                    unsigned short* __restrict__ V) {
  int h = blockIdx.x, mt = blockIdx.y;       // mt in [0,8)
  #pragma unroll
  for (int i = 0; i < 2; ++i) {
    int j = i * 256 + threadIdx.x;           // 0..511
    int ks = j >> 6, ln = (j >> 2) & 15, lg = j & 3;
    int row = mt * 16 + ln;
    int dir = row >> 6, nc = row & 63;
    int n = nc >> 1, comp = nc & 1;
    int idx = h * NHD + n;
    float arn = P[8*HN + idx], ain = P[9*HN + idx];
    short8 vv;
    #pragma unroll
    for (int e = 0; e < 8; ++e) {
      int s = ks * 32 + lg * 8 + e;
      float d = (float)(dir ? s : (LC - 1 - s));
      float m = __expf(d * arn);
      float ph = d * ain;
      float v = m * (comp ? sinf(ph) : cosf(ph));
      vv[e] = (short)f2bf(v);
    }
    ((short8*)V)[(size_t)(h * 8 + mt) * 512 + j] = vv;
  }
}

// ---------------------------------------------------------------------------
// x (L,B,H) f32 -> UF fragment-order bf16: chunk (((h*32+it)*8+ks)*16+ln)*4+lg
// = u[b][h][l = g*256 + ks*32 + lg*8 + e], inst = b*32+g = it*16+ln.
// ---------------------------------------------------------------------------
__global__ __launch_bounds__(256) void transpose_kernel(const float* __restrict__ x,
                                                        unsigned short* __restrict__ UF) {
  __shared__ unsigned short tile[32][264];
  int b  = blockIdx.x;
  int lb = blockIdx.y * 32;
  int tid = threadIdx.x;
  int g = lb >> 8, ks = (lb & 255) >> 5;
  int inst = b * 32 + g, it = inst >> 4, lnw = inst & 15;
  #pragma unroll
  for (int i = 0; i < 8; ++i) {
    int idx = i * 256 + tid;                 // 0..2047
    int row = idx >> 6, c4 = idx & 63;
    float4 v = *(const float4*)(x + (size_t)(lb + row) * BH + b * 256 + c4 * 4);
    ushort4 u4v;
    u4v.x = f2bf(v.x); u4v.y = f2bf(v.y); u4v.z = f2bf(v.z); u4v.w = f2bf(v.w);
    *(ushort4*)&tile[row][c4 * 4] = u4v;
  }
  __syncthreads();
  short8* out = (short8*)UF;
  #pragma unroll
  for (int i = 0; i < 4; ++i) {
    int j = i * 256 + tid;                   // 0..1023
    int h = j >> 2, lg = j & 3;
    short8 vv;
    #pragma unroll
    for (int e = 0; e < 8; ++e) vv[e] = (short)tile[lg * 8 + e][h];
    out[(size_t)(h * 32 + it) * 512 + ks * 64 + lnw * 4 + lg] = vv;
  }
}

// ---------------------------------------------------------------------------
// B-fragment loaders (shared by sfin / yloc): contiguous 1KB wave-loads.
// ---------------------------------------------------------------------------
__device__ __forceinline__ void load_bu(const short8* __restrict__ U8, int h, int it,
                                        int ln, int lg, short8 (&Bf)[8]) {
  size_t ub = (size_t)(h * 32 + it) * 512 + ln * 4 + lg;
  #pragma unroll
  for (int ks = 0; ks < 8; ++ks) Bf[ks] = U8[ub + ks * 64];
}
__device__ __forceinline__ void load_bs(const short8* __restrict__ S8, int h, int it,
                                        int ln, int lg, short8 (&Sf)[4]) {
  size_t sb = (size_t)(h * 32 + it) * 256 + ln * 4 + lg;
  #pragma unroll
  for (int ks = 0; ks < 4; ++ks) Sf[ks] = S8[sb + ks * 64];
}

// ---------------------------------------------------------------------------
// Chunk-final states: Sfin[h][inst][k] f32 = V'_h . u.
// ONE block per h (grid 256, 512 thr / 8 waves). Wave w owns mt=w; V-fragments
// register-resident for all 32 itiles (V'_h read ONCE from HBM). 2-stage
// B prefetch hides HBM latency.
// ---------------------------------------------------------------------------
__global__ __launch_bounds__(512, 2) void sfin_mfma(const unsigned short* __restrict__ V,
                                                    const unsigned short* __restrict__ UF,
                                                    float* __restrict__ Sfin) {
  int tid = threadIdx.x, w = tid >> 6, lane = tid & 63;
  int ln = lane & 15, lg = lane >> 4;
  int h = blockIdx.x;
  const short8* U8 = (const short8*)UF;
  const short8* V8 = (const short8*)V;

  short8 Vf[8];
  size_t vb = (size_t)(h * 8 + w) * 512 + ln * 4 + lg;
  #pragma unroll
  for (int ks = 0; ks < 8; ++ks) Vf[ks] = V8[vb + ks * 64];

  short8 BfA[8], BfB[8];
  load_bu(U8, h, 0, ln, lg, BfA);

  for (int it = 0; it < 32; it += 2) {
    load_bu(U8, h, it + 1, ln, lg, BfB);
    {
      floatx4 acc = (floatx4){0.f, 0.f, 0.f, 0.f};
      #pragma unroll
      for (int ks = 0; ks < 8; ++ks)
        acc = __builtin_amdgcn_mfma_f32_16x16x32_bf16(Vf[ks], BfA[ks], acc, 0, 0, 0);
      float* sp = Sfin + ((size_t)h * NINST + it * 16 + ln) * 128 + w * 16 + lg * 4;
      *(float4*)sp = (float4){acc[0], acc[1], acc[2], acc[3]};
    }
    if (it + 2 < 32) load_bu(U8, h, it + 2, ln, lg, BfA);
    {
      floatx4 acc = (floatx4){0.f, 0.f, 0.f, 0.f};
      #pragma unroll
      for (int ks = 0; ks < 8; ++ks)
        acc = __builtin_amdgcn_mfma_f32_16x16x32_bf16(Vf[ks], BfB[ks], acc, 0, 0, 0);
      float* sp = Sfin + ((size_t)h * NINST + (it + 1) * 16 + ln) * 128 + w * 16 + lg * 4;
      *(float4*)sp = (float4){acc[0], acc[1], acc[2], acc[3]};
    }
  }
}

// ---------------------------------------------------------------------------
// Cross-chunk scan: Sfin -> incoming states, written in Sc' fragment order:
// chunk (((h*32+it)*4+ks)*16+ln)*4+lg, k = ks*32+lg*8+e.
// ---------------------------------------------------------------------------
__global__ __launch_bounds__(256) void scanB_kernel(const float* __restrict__ P,
                                                    const float* __restrict__ Sfin,
                                                    unsigned short* __restrict__ Sc) {
  int t = blockIdx.x * 256 + threadIdx.x;
  if (t >= BH * NHD) return;
  int n = t & 31, h = (t >> 5) & 255, b = t >> 13;
  float wlr = P[6*HN + h*NHD + n], wli = P[7*HN + h*NHD + n];
  unsigned* sc = (unsigned*)Sc;
  {
    int k = 2 * n;
    int ks = k >> 5, lg = (k & 31) >> 3, eh = (k & 7) >> 1;
    float ar = 0.f, ai = 0.f;
    for (int g = 0; g < NG; ++g) {
      int inst = b * NG + g;
      int it = inst >> 4, ln = inst & 15;
      size_t chunk = (size_t)(h * 32 + it) * 256 + ks * 64 + ln * 4 + lg;
      sc[chunk * 4 + eh] = packbf2(ar, ai);
      const float* sp = Sfin + ((size_t)h * NINST + inst) * 128 + 2 * n;
      float lr = sp[0], li = sp[1];
      float nr = lr + wlr * ar - wli * ai;
      float ni = li + wlr * ai + wli * ar;
      ar = nr; ai = ni;
    }
  }
  {
    int k = 64 + 2 * n;
    int ks = k >> 5, lg = (k & 31) >> 3, eh = (k & 7) >> 1;
    float ar = 0.f, ai = 0.f;
    for (int g = NG - 1; g >= 0; --g) {
      int inst = b * NG + g;
      int it = inst >> 4, ln = inst & 15;
      size_t chunk = (size_t)(h * 32 + it) * 256 + ks * 64 + ln * 4 + lg;
      sc[chunk * 4 + eh] = packbf2(ar, ai);
      const float* sp = Sfin + ((size_t)h * NINST + inst) * 128 + 64 + 2 * n;
      float lr = sp[0], li = sp[1];
      float nr = lr + wlr * ar - wli * ai;
      float ni = li + wlr * ai + wli * ar;
      ar = nr; ai = ni;
    }
  }
}

// ---------------------------------------------------------------------------
// Fused local Toeplitz conv + correction + gelu: y = gelu(T'_h.u + E'_h.Sc).
// ONE block per h (grid 256, 512 thr / 8 waves). Wave w owns tt = {2w, 2w+1};
// T/E fragments register-resident (T'_h+E'_h read ONCE from HBM); loop 32
// itiles with 2-stage B prefetch.
// ---------------------------------------------------------------------------
__device__ __forceinline__ void comp_y(const short8 (&Tf)[2][8], const short8 (&Ef)[2][4],
                                       const short8 (&Bf)[8], const short8 (&Sf)[4],
                                       int h, int it, int w, int ln, int lg,
                                       unsigned short* __restrict__ Y2) {
  int inst = it * 16 + ln, bb = inst >> 5, g = inst & 31;
  unsigned short* yrow = Y2 + (size_t)(bb * 256 + h) * LL + g * 256;
  #pragma unroll
  for (int t2 = 0; t2 < 2; ++t2) {
    int tt = w * 2 + t2;
    floatx4 acc = (floatx4){0.f, 0.f, 0.f, 0.f};
    #pragma unroll
    for (int ks = 0; ks < 8; ++ks)
      acc = __builtin_amdgcn_mfma_f32_16x16x32_bf16(Tf[t2][ks], Bf[ks], acc, 0, 0, 0);
    #pragma unroll
    for (int ks = 0; ks < 4; ++ks)
      acc = __builtin_amdgcn_mfma_f32_16x16x32_bf16(Ef[t2][ks], Sf[ks], acc, 0, 0, 0);
    float y0 = gelu_t(acc[0]), y1 = gelu_t(acc[1]);
    float y2v = gelu_t(acc[2]), y3 = gelu_t(acc[3]);
    uint2 vv; vv.x = packbf2(y0, y1); vv.y = packbf2(y2v, y3);
    *(uint2*)(yrow + tt * 16 + lg * 4) = vv;
  }
}

__global__ __launch_bounds__(512, 2) void yloc_corr(const unsigned short* __restrict__ T,
                                                    const unsigned short* __restrict__ E,
                                                    const unsigned short* __restrict__ Sc,
                                                    const unsigned short* __restrict__ UF,
                                                    unsigned short* __restrict__ Y2) {
  int tid = threadIdx.x, w = tid >> 6, lane = tid & 63;
  int ln = lane & 15, lg = lane >> 4;
  int h = blockIdx.x;
  const short8* T8 = (const short8*)T;
  const short8* E8 = (const short8*)E;
  const short8* S8 = (const short8*)Sc;
  const short8* U8 = (const short8*)UF;

  short8 Tf[2][8], Ef[2][4];
  #pragma unroll
  for (int t2 = 0; t2 < 2; ++t2) {
    int tt = w * 2 + t2;
    size_t tb = (size_t)(h * 16 + tt) * 512 + ln * 4 + lg;
    #pragma unroll
    for (int ks = 0; ks < 8; ++ks) Tf[t2][ks] = T8[tb + ks * 64];
    size_t eb = (size_t)(h * 16 + tt) * 256 + ln * 4 + lg;
    #pragma unroll
    for (int ks = 0; ks < 4; ++ks) Ef[t2][ks] = E8[eb + ks * 64];
  }

  short8 BfA[8], SfA[4], BfB[8], SfB[4];
  load_bu(U8, h, 0, ln, lg, BfA);
  load_bs(S8, h, 0, ln, lg, SfA);

  for (int it = 0; it < 32; it += 2) {
    load_bu(U8, h, it + 1, ln, lg, BfB);
    load_bs(S8, h, it + 1, ln, lg, SfB);
    comp_y(Tf, Ef, BfA, SfA, h, it, w, ln, lg, Y2);
    if (it + 2 < 32) {
      load_bu(U8, h, it + 2, ln, lg, BfA);
      load_bs(S8, h, it + 2, ln, lg, SfA);
    }
    comp_y(Tf, Ef, BfB, SfB, h, it + 1, w, ln, lg, Y2);
  }
}

// ---------------------------------------------------------------------------
// Y2 (B*H, L) bf16 -> Yb (B*L, H) bf16
// ---------------------------------------------------------------------------
__global__ void convT_kernel(const unsigned short* __restrict__ Y2,
                             unsigned short* __restrict__ Yb) {
  __shared__ unsigned short tile[32][33];
  int pb = blockIdx.x * 32;
  int lb = blockIdx.y * 32;
  int tx = threadIdx.x, ty = threadIdx.y;
  #pragma unroll
  for (int k2 = 0; k2 < 4; ++k2)
    tile[ty + 8*k2][tx] = Y2[(size_t)(pb + ty + 8*k2) * LL + lb + tx];
  __syncthreads();
  int b = pb >> 8, h0 = pb & 255;
  #pragma unroll
  for (int k2 = 0; k2 < 4; ++k2) {
    int r = ty + 8*k2;
    Yb[(size_t)(b * LL + lb + r) * HH + h0 + tx] = tile[tx][r];
  }
}

// ---------------------------------------------------------------------------
// MFMA GEMM + GLU (LDS-staged XOR-swizzled B; A now fragment-order Wf)
// ---------------------------------------------------------------------------
__global__ __launch_bounds__(1024, 4) void gemm_mfma(
    const unsigned short* __restrict__ Wf,
    const unsigned short* __restrict__ Yb,
    const float* __restrict__ bvec, float* __restrict__ out) {
  __shared__ __align__(16) unsigned short lds[32768];   // 64 KB
  int tid  = threadIdx.x;
  int w    = tid >> 6;
  int lane = tid & 63;
  int ln = lane & 15, lg = lane >> 4;
  int b  = blockIdx.x >> 6;
  int l0 = (blockIdx.x & 63) << 7;

  const short8* W8 = (const short8*)Wf;

  {
    int r  = tid >> 3;
    int c0 = (tid & 7) * 4;
    const short8* src = (const short8*)Yb + (size_t)(b * LL + l0 + r) * 32;
    short8* dst = (short8*)lds + r * 32;
    #pragma unroll
    for (int k = 0; k < 4; ++k) {
      int c = c0 + k;
      dst[c ^ (r & 7)] = src[c];
    }
  }
  __syncthreads();

  int mgrp = w >> 1, ngrp = w & 1;
  floatx4 acc[4][4];
  #pragma unroll
  for (int m = 0; m < 4; ++m)
    #pragma unroll
    for (int n = 0; n < 4; ++n) acc[m][n] = (floatx4){0.f, 0.f, 0.f, 0.f};

  const short8* L8 = (const short8*)lds;
  #pragma unroll
  for (int ks = 0; ks < 8; ++ks) {
    short8 Bf[4];
    #pragma unroll
    for (int nf = 0; nf < 4; ++nf) {
      int row = ngrp * 64 + nf * 16 + ln;
      Bf[nf] = L8[row * 32 + ((ks * 4 + lg) ^ (row & 7))];
    }
    #pragma unroll
    for (int mm = 0; mm < 4; ++mm) {
      int og = mgrp * 2 + (mm & 1) + (mm >> 1) * 16;     // o-row group /16
      short8 Af = W8[(size_t)(og * 8 + ks) * 64 + ln * 4 + lg];
      #pragma unroll
      for (int nf = 0; nf < 4; ++nf)
        acc[mm][nf] = __builtin_amdgcn_mfma_f32_16x16x32_bf16(Af, Bf[nf], acc[mm][nf], 0, 0, 0);
    }
  }

  #pragma unroll
  for (int mm = 0; mm < 2; ++mm) {
    int obase = mgrp * 32 + mm * 16 + lg * 4;
    #pragma unroll
    for (int r = 0; r < 4; ++r) {
      int o = obase + r;
      float b0 = bvec[o];
      float b1 = bvec[HH + o];
      float* op = out + ((size_t)(b * HH + o)) * LL + l0 + ngrp * 64 + ln;
      #pragma unroll
      for (int nf = 0; nf < 4; ++nf) {
        float z1 = acc[mm][nf][r] + b0;
        float z2 = acc[mm + 2][nf][r] + b1;
        op[nf * 16] = z1 / (1.f + __expf(-z2));
      }
    }
  }
}

// ---------------------------------------------------------------------------
extern "C" void kernel_launch(void* const* d_in, const int* in_sizes, int n_in,
                              void* d_out, int out_size, void* d_ws, size_t ws_size,
                              hipStream_t stream) {
  const float* x      = (const float*)d_in[0];
  const float* log_dt = (const float*)d_in[1];
  const float* A_real = (const float*)d_in[2];
  const float* A_imag = (const float*)d_in[3];
  const float* C_real = (const float*)d_in[4];
  const float* C_imag = (const float*)d_in[5];
  const float* Dv     = (const float*)d_in[6];
  const float* W      = (const float*)d_in[7];
  const float* bvec   = (const float*)d_in[8];
  float* out = (float*)d_out;

  // d_out doubles as scratch (serial: write -> read -> full overwrite by gemm):
  //   Y2   = d_out[0 : 64MiB)   bf16 (B*H, L), written by yloc, read by convT
  //   Sfin = d_out[64 : 128MiB) f32, written by sfin, read by scanB
  unsigned short* Y2   = (unsigned short*)d_out;
  float*          Sfin = (float*)d_out + 16777216;

  // ws: all regions dedicated (no aliasing). Total 226 MiB.
  char* ws = (char*)d_ws;
  float*          P  = (float*)ws;                          // 320 KB
  unsigned short* Wf = (unsigned short*)(ws + 524288);      // 256 KB
  float*          Kf = (float*)(ws + 786432);               // 256 KB
  float*          Kb = (float*)(ws + 1048576);              // 256 KB
  size_t OFF_UF = (size_t)2 << 20;                          // [2, 66) MiB
  size_t OFF_T  = OFF_UF + ((size_t)256 * 32 * 512 * 16);   // [66, 98) MiB
  size_t OFF_E  = OFF_T + ((size_t)256 * 16 * 512 * 16);    // [98, 114) MiB
  size_t OFF_V  = OFF_E + ((size_t)256 * 16 * 256 * 16);    // [114, 130) MiB
  size_t OFF_SC = OFF_V + ((size_t)256 * 8 * 512 * 16);     // [130, 162) MiB
  size_t OFF_YB = OFF_SC + ((size_t)256 * 32 * 256 * 16);   // [162, 226) MiB
  unsigned short* UF = (unsigned short*)(ws + OFF_UF);
  unsigned short* T  = (unsigned short*)(ws + OFF_T);
  unsigned short* E  = (unsigned short*)(ws + OFF_E);
  unsigned short* V  = (unsigned short*)(ws + OFF_V);
  unsigned short* Sc = (unsigned short*)(ws + OFF_SC);
  unsigned short* Yb = (unsigned short*)(ws + OFF_YB);

  precomp_kernel<<<HN / 256, 256, 0, stream>>>(log_dt, A_real, A_imag, C_real, C_imag, P);
  wt_frag_kernel<<<32, 256, 0, stream>>>(W, Wf);
  kprep_kernel<<<HH * 256 / 256, 256, 0, stream>>>(P, Kf, Kb);
  tprep_kernel<<<dim3(HH, 16), 256, 0, stream>>>(Kf, Kb, Dv, T);
  eprep_kernel<<<dim3(HH, 16), 256, 0, stream>>>(P, E);
  vprep_kernel<<<dim3(HH, 8), 256, 0, stream>>>(P, V);
  transpose_kernel<<<dim3(BB, LL / 32), 256, 0, stream>>>(x, UF);
  sfin_mfma<<<HH, 512, 0, stream>>>(V, UF, Sfin);
  scanB_kernel<<<(BH * NHD) / 256, 256, 0, stream>>>(P, Sfin, Sc);
  yloc_corr<<<HH, 512, 0, stream>>>(T, E, Sc, UF, Y2);
  convT_kernel<<<dim3(BH / 32, LL / 32), dim3(32, 8), 0, stream>>>(Y2, Yb);
  gemm_mfma<<<BB * (LL / 128), 1024, 0, stream>>>(Wf, Yb, bvec, out);
}

// Round 12
// 307.860 us; speedup vs baseline: 3.0019x; 1.1755x over previous
//
#include <hip/hip_runtime.h>
#include <hip/hip_bf16.h>
#include <math.h>

#define HH  256      // d_model
#define NHD 32       // state halves
#define LL  8192     // sequence length
#define BB  16       // batch
#define HN  (HH*NHD) // 8192
#define BH  (BB*HH)  // 4096
#define LC  256      // chunk length
#define NG  (LL/LC)  // 32 chunks per row
#define NINST (BB*NG) // 512 chunk instances per h

typedef __attribute__((ext_vector_type(8))) short short8;
typedef __attribute__((ext_vector_type(4))) float floatx4;

__device__ __forceinline__ unsigned short f2bf(float f) {
  unsigned u = __float_as_uint(f);
  unsigned r = (u + 0x7FFF + ((u >> 16) & 1)) >> 16;
  return (unsigned short)r;
}
__device__ __forceinline__ unsigned packbf2(float a, float b) {
  return (unsigned)f2bf(a) | ((unsigned)f2bf(b) << 16);
}
__device__ __forceinline__ float gelu_t(float y) {
  float y2 = y * y;
  float arg = 1.5957691216f * fmaf(0.044715f * y2, y, y);
  return y / (1.f + __expf(-arg));
}

// ---------------------------------------------------------------------------
// Param precompute. P[k*HN + h*NHD + n]:
// 0=wr 1=wi 2=c0r 3=c0i 4=c1r 5=c1i 6=wLr 7=wLi 8=ar(dtA re) 9=ai(dtA im)
// ---------------------------------------------------------------------------
__global__ void precomp_kernel(const float* __restrict__ log_dt,
                               const float* __restrict__ A_real,
                               const float* __restrict__ A_imag,
                               const float* __restrict__ C_real,
                               const float* __restrict__ C_imag,
                               float* __restrict__ P) {
  int i = blockIdx.x * blockDim.x + threadIdx.x;
  if (i >= HN) return;
  int h = i >> 5;
  double dt  = exp((double)log_dt[h]);
  double Are = -exp((double)A_real[i]);
  double Aim = (double)A_imag[i];
  double ar = Are * dt, ai = Aim * dt;
  double ea = exp(ar);
  double wr = ea * cos(ai), wi = ea * sin(ai);
  double em_r = wr - 1.0, em_i = wi;
  double den = Are * Are + Aim * Aim;
  double rr = (em_r * Are + em_i * Aim) / den;
  double ri = (em_i * Are - em_r * Aim) / den;
  P[0*HN + i] = (float)wr;
  P[1*HN + i] = (float)wi;
  {
    double cr = (double)C_real[i], ci = (double)C_imag[i];
    P[2*HN + i] = (float)(2.0 * (cr * rr - ci * ri));
    P[3*HN + i] = (float)(2.0 * (cr * ri + ci * rr));
  }
  {
    double cr = (double)C_real[HN + i], ci = (double)C_imag[HN + i];
    P[4*HN + i] = (float)(2.0 * (cr * rr - ci * ri));
    P[5*HN + i] = (float)(2.0 * (cr * ri + ci * rr));
  }
  {
    double arL = ar * (double)LC, aiL = ai * (double)LC;
    double eaL = exp(arL);
    P[6*HN + i] = (float)(eaL * cos(aiL));
    P[7*HN + i] = (float)(eaL * sin(aiL));
  }
  P[8*HN + i] = (float)ar;
  P[9*HN + i] = (float)ai;
}

// ---------------------------------------------------------------------------
// W (512,256) f32 -> Wf fragment-order bf16:
// chunk ((og*8+ks)*16+ln)*4+lg holds W[og*16+ln][ks*32+lg*8+e], e in [0,8).
// ---------------------------------------------------------------------------
__global__ __launch_bounds__(256) void wt_frag_kernel(const float* __restrict__ W,
                                                      unsigned short* __restrict__ Wf) {
  int og = blockIdx.x;                       // 0..31
  #pragma unroll
  for (int i = 0; i < 2; ++i) {
    int j = i * 256 + threadIdx.x;           // 0..511 = ks*64 + ln*4 + lg
    int ks = j >> 6, ln = (j >> 2) & 15, lg = j & 3;
    const float* src = W + (size_t)(og * 16 + ln) * 256 + ks * 32 + lg * 8;
    short8 vv;
    #pragma unroll
    for (int e = 0; e < 8; ++e) vv[e] = (short)f2bf(src[e]);
    ((short8*)Wf)[og * 512 + j] = vv;
  }
}

// ---------------------------------------------------------------------------
// kf/kb tables: kf[h][d] = sum_n Re(c0_n w_n^d), kb same with c1.
// ---------------------------------------------------------------------------
__global__ __launch_bounds__(256) void kprep_kernel(const float* __restrict__ P,
                                                    float* __restrict__ Kf,
                                                    float* __restrict__ Kb) {
  int i = blockIdx.x * 256 + threadIdx.x;   // h*256 + d
  int d = i & 255, h = i >> 8;
  float fd = (float)d;
  float sf = 0.f, sb = 0.f;
  #pragma unroll 4
  for (int n = 0; n < NHD; ++n) {
    int j = h * NHD + n;
    float m  = __expf(fd * P[8*HN + j]);
    float ph = fd * P[9*HN + j];
    float cs = cosf(ph), sn = sinf(ph);
    float re = m * cs, im = m * sn;
    sf += P[2*HN + j] * re - P[3*HN + j] * im;
    sb += P[4*HN + j] * re - P[5*HN + j] * im;
  }
  Kf[i] = sf;
  Kb[i] = sb;
}

// ---------------------------------------------------------------------------
// T' fragment-order: chunk idx (((h*16+tt)*8+ks)*16+ln)*4+lg holds
// T[t=tt*16+ln][s=ks*32+lg*8+e], e in [0,8).
// ---------------------------------------------------------------------------
__global__ __launch_bounds__(256) void tprep_kernel(const float* __restrict__ Kf,
                                                    const float* __restrict__ Kb,
                                                    const float* __restrict__ Dv,
                                                    unsigned short* __restrict__ T) {
  int h = blockIdx.x, tt = blockIdx.y;
  const float* kf = Kf + h * 256;
  const float* kb = Kb + h * 256;
  float dh = Dv[h];
  short8* out = (short8*)T;
  #pragma unroll
  for (int i = 0; i < 2; ++i) {
    int j = i * 256 + threadIdx.x;          // 0..511 = ks*64 + ln*4 + lg
    int ks = j >> 6, ln = (j >> 2) & 15, lg = j & 3;
    int t = tt * 16 + ln;
    short8 vv;
    #pragma unroll
    for (int e = 0; e < 8; ++e) {
      int s = ks * 32 + lg * 8 + e;
      int d = t - s;
      float v = (d > 0) ? kf[d] : ((d < 0) ? kb[-d - 1] : (kf[0] + dh));
      vv[e] = (short)f2bf(v);
    }
    out[(size_t)(h * 16 + tt) * 512 + j] = vv;
  }
}

// ---------------------------------------------------------------------------
// E' fragment-order: chunk (((h*16+tt)*4+ks)*16+ln)*4+lg holds E[t][k],
// t=tt*16+ln, k=ks*32+lg*8+e. k<64: pairs (Re, -Im) of c0*w^{t+1};
// k>=64: pairs of c1*w^{LC-1-t}. Direct exp.
// ---------------------------------------------------------------------------
__global__ __launch_bounds__(256) void eprep_kernel(const float* __restrict__ P,
                                                    unsigned short* __restrict__ E) {
  int h = blockIdx.x, tt = blockIdx.y;
  int j = threadIdx.x;                       // 0..255 = ks*64 + ln*4 + lg
  int ks = j >> 6, ln = (j >> 2) & 15, lg = j & 3;
  int t = tt * 16 + ln;
  int k0 = ks * 32 + lg * 8;
  short8 vv;
  if (k0 < 64) {
    float d = (float)(t + 1);
    #pragma unroll
    for (int q = 0; q < 4; ++q) {
      int n = (k0 >> 1) + q;
      int idx = h * NHD + n;
      float m  = __expf(d * P[8*HN + idx]);
      float ph = d * P[9*HN + idx];
      float re = m * cosf(ph), im = m * sinf(ph);
      float cr = P[2*HN + idx], ci = P[3*HN + idx];
      float zr = cr * re - ci * im;
      float zi = cr * im + ci * re;
      vv[2*q]   = (short)f2bf(zr);
      vv[2*q+1] = (short)f2bf(-zi);
    }
  } else {
    float d = (float)(LC - 1 - t);
    #pragma unroll
    for (int q = 0; q < 4; ++q) {
      int n = ((k0 - 64) >> 1) + q;
      int idx = h * NHD + n;
      float m  = __expf(d * P[8*HN + idx]);
      float ph = d * P[9*HN + idx];
      float re = m * cosf(ph), im = m * sinf(ph);
      float cr = P[4*HN + idx], ci = P[5*HN + idx];
      float zr = cr * re - ci * im;
      float zi = cr * im + ci * re;
      vv[2*q]   = (short)f2bf(zr);
      vv[2*q+1] = (short)f2bf(-zi);
    }
  }
  ((short8*)E)[(size_t)(h * 16 + tt) * 256 + j] = vv;
}

// ---------------------------------------------------------------------------
// V' fragment-order: chunk (((h*8+mt)*8+ks)*16+ln)*4+lg, row=mt*16+ln:
// row<64: comp(row&1) of w^{LC-1-s}; row>=64: comp of w^s; s=ks*32+lg*8+e.
// ---------------------------------------------------------------------------
__global__ __launch_bounds__(256) void vprep_kernel(const float* __restrict__ P,
                                                    unsigned short* __restrict__ V) {
  int h = blockIdx.x, mt = blockIdx.y;       // mt in [0,8)
  #pragma unroll
  for (int i = 0; i < 2; ++i) {
    int j = i * 256 + threadIdx.x;           // 0..511
    int ks = j >> 6, ln = (j >> 2) & 15, lg = j & 3;
    int row = mt * 16 + ln;
    int dir = row >> 6, nc = row & 63;
    int n = nc >> 1, comp = nc & 1;
    int idx = h * NHD + n;
    float arn = P[8*HN + idx], ain = P[9*HN + idx];
    short8 vv;
    #pragma unroll
    for (int e = 0; e < 8; ++e) {
      int s = ks * 32 + lg * 8 + e;
      float d = (float)(dir ? s : (LC - 1 - s));
      float m = __expf(d * arn);
      float ph = d * ain;
      float v = m * (comp ? sinf(ph) : cosf(ph));
      vv[e] = (short)f2bf(v);
    }
    ((short8*)V)[(size_t)(h * 8 + mt) * 512 + j] = vv;
  }
}

// ---------------------------------------------------------------------------
// x (L,B,H) f32 -> UF fragment-order bf16: chunk (((h*32+it)*8+ks)*16+ln)*4+lg
// = u[b][h][l = g*256 + ks*32 + lg*8 + e], inst = b*32+g = it*16+ln.
// ---------------------------------------------------------------------------
__global__ __launch_bounds__(256) void transpose_kernel(const float* __restrict__ x,
                                                        unsigned short* __restrict__ UF) {
  __shared__ unsigned short tile[32][264];
  int b  = blockIdx.x;
  int lb = blockIdx.y * 32;
  int tid = threadIdx.x;
  int g = lb >> 8, ks = (lb & 255) >> 5;
  int inst = b * 32 + g, it = inst >> 4, lnw = inst & 15;
  #pragma unroll
  for (int i = 0; i < 8; ++i) {
    int idx = i * 256 + tid;                 // 0..2047
    int row = idx >> 6, c4 = idx & 63;
    float4 v = *(const float4*)(x + (size_t)(lb + row) * BH + b * 256 + c4 * 4);
    ushort4 u4v;
    u4v.x = f2bf(v.x); u4v.y = f2bf(v.y); u4v.z = f2bf(v.z); u4v.w = f2bf(v.w);
    *(ushort4*)&tile[row][c4 * 4] = u4v;
  }
  __syncthreads();
  short8* out = (short8*)UF;
  #pragma unroll
  for (int i = 0; i < 4; ++i) {
    int j = i * 256 + tid;                   // 0..1023
    int h = j >> 2, lg = j & 3;
    short8 vv;
    #pragma unroll
    for (int e = 0; e < 8; ++e) vv[e] = (short)tile[lg * 8 + e][h];
    out[(size_t)(h * 32 + it) * 512 + ks * 64 + lnw * 4 + lg] = vv;
  }
}

// ---------------------------------------------------------------------------
// B-fragment loaders (shared by sfin / yloc): contiguous 1KB wave-loads.
// ---------------------------------------------------------------------------
__device__ __forceinline__ void load_bu(const short8* __restrict__ U8, int h, int it,
                                        int ln, int lg, short8 (&Bf)[8]) {
  size_t ub = (size_t)(h * 32 + it) * 512 + ln * 4 + lg;
  #pragma unroll
  for (int ks = 0; ks < 8; ++ks) Bf[ks] = U8[ub + ks * 64];
}
__device__ __forceinline__ void load_bs(const short8* __restrict__ S8, int h, int it,
                                        int ln, int lg, short8 (&Sf)[4]) {
  size_t sb = (size_t)(h * 32 + it) * 256 + ln * 4 + lg;
  #pragma unroll
  for (int ks = 0; ks < 4; ++ks) Sf[ks] = S8[sb + ks * 64];
}

// ---------------------------------------------------------------------------
// Chunk-final states: Sfin[h][inst][k] f32 = V'_h . u.
// ONE block per h (grid 256, 512 thr / 8 waves). V'_h read ONCE from HBM.
// ---------------------------------------------------------------------------
__global__ __launch_bounds__(512, 2) void sfin_mfma(const unsigned short* __restrict__ V,
                                                    const unsigned short* __restrict__ UF,
                                                    float* __restrict__ Sfin) {
  int tid = threadIdx.x, w = tid >> 6, lane = tid & 63;
  int ln = lane & 15, lg = lane >> 4;
  int h = blockIdx.x;
  const short8* U8 = (const short8*)UF;
  const short8* V8 = (const short8*)V;

  short8 Vf[8];
  size_t vb = (size_t)(h * 8 + w) * 512 + ln * 4 + lg;
  #pragma unroll
  for (int ks = 0; ks < 8; ++ks) Vf[ks] = V8[vb + ks * 64];

  short8 BfA[8], BfB[8];
  load_bu(U8, h, 0, ln, lg, BfA);

  for (int it = 0; it < 32; it += 2) {
    load_bu(U8, h, it + 1, ln, lg, BfB);
    {
      floatx4 acc = (floatx4){0.f, 0.f, 0.f, 0.f};
      #pragma unroll
      for (int ks = 0; ks < 8; ++ks)
        acc = __builtin_amdgcn_mfma_f32_16x16x32_bf16(Vf[ks], BfA[ks], acc, 0, 0, 0);
      float* sp = Sfin + ((size_t)h * NINST + it * 16 + ln) * 128 + w * 16 + lg * 4;
      *(float4*)sp = (float4){acc[0], acc[1], acc[2], acc[3]};
    }
    if (it + 2 < 32) load_bu(U8, h, it + 2, ln, lg, BfA);
    {
      floatx4 acc = (floatx4){0.f, 0.f, 0.f, 0.f};
      #pragma unroll
      for (int ks = 0; ks < 8; ++ks)
        acc = __builtin_amdgcn_mfma_f32_16x16x32_bf16(Vf[ks], BfB[ks], acc, 0, 0, 0);
      float* sp = Sfin + ((size_t)h * NINST + (it + 1) * 16 + ln) * 128 + w * 16 + lg * 4;
      *(float4*)sp = (float4){acc[0], acc[1], acc[2], acc[3]};
    }
  }
}

// ---------------------------------------------------------------------------
// Cross-chunk scan: Sfin -> incoming states, written in Sc' fragment order.
// ---------------------------------------------------------------------------
__global__ __launch_bounds__(256) void scanB_kernel(const float* __restrict__ P,
                                                    const float* __restrict__ Sfin,
                                                    unsigned short* __restrict__ Sc) {
  int t = blockIdx.x * 256 + threadIdx.x;
  if (t >= BH * NHD) return;
  int n = t & 31, h = (t >> 5) & 255, b = t >> 13;
  float wlr = P[6*HN + h*NHD + n], wli = P[7*HN + h*NHD + n];
  unsigned* sc = (unsigned*)Sc;
  {
    int k = 2 * n;
    int ks = k >> 5, lg = (k & 31) >> 3, eh = (k & 7) >> 1;
    float ar = 0.f, ai = 0.f;
    for (int g = 0; g < NG; ++g) {
      int inst = b * NG + g;
      int it = inst >> 4, ln = inst & 15;
      size_t chunk = (size_t)(h * 32 + it) * 256 + ks * 64 + ln * 4 + lg;
      sc[chunk * 4 + eh] = packbf2(ar, ai);
      const float* sp = Sfin + ((size_t)h * NINST + inst) * 128 + 2 * n;
      float lr = sp[0], li = sp[1];
      float nr = lr + wlr * ar - wli * ai;
      float ni = li + wlr * ai + wli * ar;
      ar = nr; ai = ni;
    }
  }
  {
    int k = 64 + 2 * n;
    int ks = k >> 5, lg = (k & 31) >> 3, eh = (k & 7) >> 1;
    float ar = 0.f, ai = 0.f;
    for (int g = NG - 1; g >= 0; --g) {
      int inst = b * NG + g;
      int it = inst >> 4, ln = inst & 15;
      size_t chunk = (size_t)(h * 32 + it) * 256 + ks * 64 + ln * 4 + lg;
      sc[chunk * 4 + eh] = packbf2(ar, ai);
      const float* sp = Sfin + ((size_t)h * NINST + inst) * 128 + 64 + 2 * n;
      float lr = sp[0], li = sp[1];
      float nr = lr + wlr * ar - wli * ai;
      float ni = li + wlr * ai + wli * ar;
      ar = nr; ai = ni;
    }
  }
}

// ---------------------------------------------------------------------------
// Fused local Toeplitz conv + correction + gelu: y = gelu(T'_h.u + E'_h.Sc).
// ONE block per h; T'_h/E'_h register-resident, read ONCE from HBM.
// ---------------------------------------------------------------------------
__device__ __forceinline__ void comp_y(const short8 (&Tf)[2][8], const short8 (&Ef)[2][4],
                                       const short8 (&Bf)[8], const short8 (&Sf)[4],
                                       int h, int it, int w, int ln, int lg,
                                       unsigned short* __restrict__ Y2) {
  int inst = it * 16 + ln, bb = inst >> 5, g = inst & 31;
  unsigned short* yrow = Y2 + (size_t)(bb * 256 + h) * LL + g * 256;
  #pragma unroll
  for (int t2 = 0; t2 < 2; ++t2) {
    int tt = w * 2 + t2;
    floatx4 acc = (floatx4){0.f, 0.f, 0.f, 0.f};
    #pragma unroll
    for (int ks = 0; ks < 8; ++ks)
      acc = __builtin_amdgcn_mfma_f32_16x16x32_bf16(Tf[t2][ks], Bf[ks], acc, 0, 0, 0);
    #pragma unroll
    for (int ks = 0; ks < 4; ++ks)
      acc = __builtin_amdgcn_mfma_f32_16x16x32_bf16(Ef[t2][ks], Sf[ks], acc, 0, 0, 0);
    float y0 = gelu_t(acc[0]), y1 = gelu_t(acc[1]);
    float y2v = gelu_t(acc[2]), y3 = gelu_t(acc[3]);
    uint2 vv; vv.x = packbf2(y0, y1); vv.y = packbf2(y2v, y3);
    *(uint2*)(yrow + tt * 16 + lg * 4) = vv;
  }
}

__global__ __launch_bounds__(512, 2) void yloc_corr(const unsigned short* __restrict__ T,
                                                    const unsigned short* __restrict__ E,
                                                    const unsigned short* __restrict__ Sc,
                                                    const unsigned short* __restrict__ UF,
                                                    unsigned short* __restrict__ Y2) {
  int tid = threadIdx.x, w = tid >> 6, lane = tid & 63;
  int ln = lane & 15, lg = lane >> 4;
  int h = blockIdx.x;
  const short8* T8 = (const short8*)T;
  const short8* E8 = (const short8*)E;
  const short8* S8 = (const short8*)Sc;
  const short8* U8 = (const short8*)UF;

  short8 Tf[2][8], Ef[2][4];
  #pragma unroll
  for (int t2 = 0; t2 < 2; ++t2) {
    int tt = w * 2 + t2;
    size_t tb = (size_t)(h * 16 + tt) * 512 + ln * 4 + lg;
    #pragma unroll
    for (int ks = 0; ks < 8; ++ks) Tf[t2][ks] = T8[tb + ks * 64];
    size_t eb = (size_t)(h * 16 + tt) * 256 + ln * 4 + lg;
    #pragma unroll
    for (int ks = 0; ks < 4; ++ks) Ef[t2][ks] = E8[eb + ks * 64];
  }

  short8 BfA[8], SfA[4], BfB[8], SfB[4];
  load_bu(U8, h, 0, ln, lg, BfA);
  load_bs(S8, h, 0, ln, lg, SfA);

  for (int it = 0; it < 32; it += 2) {
    load_bu(U8, h, it + 1, ln, lg, BfB);
    load_bs(S8, h, it + 1, ln, lg, SfB);
    comp_y(Tf, Ef, BfA, SfA, h, it, w, ln, lg, Y2);
    if (it + 2 < 32) {
      load_bu(U8, h, it + 2, ln, lg, BfA);
      load_bs(S8, h, it + 2, ln, lg, SfA);
    }
    comp_y(Tf, Ef, BfB, SfB, h, it + 1, w, ln, lg, Y2);
  }
}

// ---------------------------------------------------------------------------
// MFMA GEMM + GLU, fused transpose staging: reads Y2 (h-major bf16) directly,
// transposes in LDS (raw 64-l slice, 2-pad rows), repacks into the
// XOR-swizzled fragment-order B region (byte-identical to old Yb path),
// then computes as before. convT kernel eliminated.
// ---------------------------------------------------------------------------
#define RAW_W 258   // u16 per raw row (+2 pad -> 129-word stride, conflict-lite)
__global__ __launch_bounds__(1024, 4) void gemm_mfma(
    const unsigned short* __restrict__ Wf,
    const unsigned short* __restrict__ Y2,
    const float* __restrict__ bvec, float* __restrict__ out) {
  __shared__ __align__(16) unsigned short ldsB[32768];      // 64 KB frag-order B
  __shared__ unsigned short raw[64 * RAW_W];                // ~33 KB h-major slice
  int tid  = threadIdx.x;
  int w    = tid >> 6;
  int lane = tid & 63;
  int ln = lane & 15, lg = lane >> 4;
  int b  = blockIdx.x >> 6;
  int l0 = (blockIdx.x & 63) << 7;

  const short8* W8 = (const short8*)Wf;

  // --- fused transpose staging: 2 slices of 64 l-columns ---
  #pragma unroll
  for (int sl = 0; sl < 2; ++sl) {
    {
      int h = tid >> 2, lc = tid & 3;   // h 0..255, lc selects 16 l
      const unsigned short* src = Y2 + (((size_t)(b * 256 + h)) << 13) + l0 + sl * 64 + lc * 16;
      short8 v0 = ((const short8*)src)[0];
      short8 v1 = ((const short8*)src)[1];
      #pragma unroll
      for (int e = 0; e < 8; ++e) raw[(lc * 16 + e) * RAW_W + h] = (unsigned short)v0[e];
      #pragma unroll
      for (int e = 0; e < 8; ++e) raw[(lc * 16 + 8 + e) * RAW_W + h] = (unsigned short)v1[e];
    }
    __syncthreads();
    {
      int c = tid & 31, lq = tid >> 5;  // c = h-chunk (8 h), lq 0..31
      #pragma unroll
      for (int s2 = 0; s2 < 2; ++s2) {
        int lpp = lq + s2 * 32;         // l within slice
        int l = sl * 64 + lpp;          // tile row
        short8 vv;
        #pragma unroll
        for (int e = 0; e < 8; ++e) vv[e] = (short)raw[lpp * RAW_W + c * 8 + e];
        ((short8*)ldsB)[l * 32 + (c ^ (l & 7))] = vv;
      }
    }
    __syncthreads();
  }

  // --- compute (identical to proven R10 path) ---
  int mgrp = w >> 1, ngrp = w & 1;
  floatx4 acc[4][4];
  #pragma unroll
  for (int m = 0; m < 4; ++m)
    #pragma unroll
    for (int n = 0; n < 4; ++n) acc[m][n] = (floatx4){0.f, 0.f, 0.f, 0.f};

  const short8* L8 = (const short8*)ldsB;
  #pragma unroll
  for (int ks = 0; ks < 8; ++ks) {
    short8 Bf[4];
    #pragma unroll
    for (int nf = 0; nf < 4; ++nf) {
      int row = ngrp * 64 + nf * 16 + ln;
      Bf[nf] = L8[row * 32 + ((ks * 4 + lg) ^ (row & 7))];
    }
    #pragma unroll
    for (int mm = 0; mm < 4; ++mm) {
      int og = mgrp * 2 + (mm & 1) + (mm >> 1) * 16;     // o-row group /16
      short8 Af = W8[(size_t)(og * 8 + ks) * 64 + ln * 4 + lg];
      #pragma unroll
      for (int nf = 0; nf < 4; ++nf)
        acc[mm][nf] = __builtin_amdgcn_mfma_f32_16x16x32_bf16(Af, Bf[nf], acc[mm][nf], 0, 0, 0);
    }
  }

  #pragma unroll
  for (int mm = 0; mm < 2; ++mm) {
    int obase = mgrp * 32 + mm * 16 + lg * 4;
    #pragma unroll
    for (int r = 0; r < 4; ++r) {
      int o = obase + r;
      float b0 = bvec[o];
      float b1 = bvec[HH + o];
      float* op = out + ((size_t)(b * HH + o)) * LL + l0 + ngrp * 64 + ln;
      #pragma unroll
      for (int nf = 0; nf < 4; ++nf) {
        float z1 = acc[mm][nf][r] + b0;
        float z2 = acc[mm + 2][nf][r] + b1;
        op[nf * 16] = z1 / (1.f + __expf(-z2));
      }
    }
  }
}

// ---------------------------------------------------------------------------
extern "C" void kernel_launch(void* const* d_in, const int* in_sizes, int n_in,
                              void* d_out, int out_size, void* d_ws, size_t ws_size,
                              hipStream_t stream) {
  const float* x      = (const float*)d_in[0];
  const float* log_dt = (const float*)d_in[1];
  const float* A_real = (const float*)d_in[2];
  const float* A_imag = (const float*)d_in[3];
  const float* C_real = (const float*)d_in[4];
  const float* C_imag = (const float*)d_in[5];
  const float* Dv     = (const float*)d_in[6];
  const float* W      = (const float*)d_in[7];
  const float* bvec   = (const float*)d_in[8];
  float* out = (float*)d_out;

  // d_out doubles as scratch for Sfin only (serial: sfin writes -> scanB reads
  // -> gemm overwrites all of d_out last):
  float* Sfin = (float*)d_out + 16777216;   // d_out[64:128MiB)

  // ws: all regions dedicated (no aliasing). Total 226 MiB.
  char* ws = (char*)d_ws;
  float*          P  = (float*)ws;                          // 320 KB
  unsigned short* Wf = (unsigned short*)(ws + 524288);      // 256 KB
  float*          Kf = (float*)(ws + 786432);               // 256 KB
  float*          Kb = (float*)(ws + 1048576);              // 256 KB
  size_t OFF_UF = (size_t)2 << 20;                          // [2, 66) MiB
  size_t OFF_T  = OFF_UF + ((size_t)256 * 32 * 512 * 16);   // [66, 98) MiB
  size_t OFF_E  = OFF_T + ((size_t)256 * 16 * 512 * 16);    // [98, 114) MiB
  size_t OFF_V  = OFF_E + ((size_t)256 * 16 * 256 * 16);    // [114, 130) MiB
  size_t OFF_SC = OFF_V + ((size_t)256 * 8 * 512 * 16);     // [130, 162) MiB
  size_t OFF_Y2 = OFF_SC + ((size_t)256 * 32 * 256 * 16);   // [162, 226) MiB
  unsigned short* UF = (unsigned short*)(ws + OFF_UF);
  unsigned short* T  = (unsigned short*)(ws + OFF_T);
  unsigned short* E  = (unsigned short*)(ws + OFF_E);
  unsigned short* V  = (unsigned short*)(ws + OFF_V);
  unsigned short* Sc = (unsigned short*)(ws + OFF_SC);
  unsigned short* Y2 = (unsigned short*)(ws + OFF_Y2);

  precomp_kernel<<<HN / 256, 256, 0, stream>>>(log_dt, A_real, A_imag, C_real, C_imag, P);
  wt_frag_kernel<<<32, 256, 0, stream>>>(W, Wf);
  kprep_kernel<<<HH * 256 / 256, 256, 0, stream>>>(P, Kf, Kb);
  tprep_kernel<<<dim3(HH, 16), 256, 0, stream>>>(Kf, Kb, Dv, T);
  eprep_kernel<<<dim3(HH, 16), 256, 0, stream>>>(P, E);
  vprep_kernel<<<dim3(HH, 8), 256, 0, stream>>>(P, V);
  transpose_kernel<<<dim3(BB, LL / 32), 256, 0, stream>>>(x, UF);
  sfin_mfma<<<HH, 512, 0, stream>>>(V, UF, Sfin);
  scanB_kernel<<<(BH * NHD) / 256, 256, 0, stream>>>(P, Sfin, Sc);
  yloc_corr<<<HH, 512, 0, stream>>>(T, E, Sc, UF, Y2);
  gemm_mfma<<<BB * (LL / 128), 1024, 0, stream>>>(Wf, Y2, bvec, out);
}